// Round 2
// baseline (991.228 us; speedup 1.0000x reference)
//
#include <hip/hip_runtime.h>
#include <cfloat>

// Problem constants
// z: [16,4096,256] fp32 -> N=65536 rows, d=256
// embedding: [256,1024], cluster_size: [1024], embedding_mean: [256,1024]
// outputs: z_q_st[16777216], vq_loss[1], embedding_new[262144],
//          cluster_size_new[1024], embedding_mean_new[262144]

#define DECAYC 0.99f
#define EPSQ 1e-5f

// ---------------- kernel 1: colnorm[k] = sum_d E[d][k]^2 ----------------
__global__ __launch_bounds__(256) void colnorm_kernel(const float* __restrict__ E,
                                                      float* __restrict__ colnorm) {
    int k = blockIdx.x * 256 + threadIdx.x;  // 0..1023
    float s = 0.f;
#pragma unroll 8
    for (int d = 0; d < 256; ++d) {
        float v = E[d * 1024 + k];
        s += v * v;
    }
    colnorm[k] = s;
}

// ---------------- kernel 1b: ET[k][d] = E[d][k] ----------------
__global__ __launch_bounds__(256) void transpose_kernel(const float* __restrict__ E,
                                                        float* __restrict__ ET) {
    int k = blockIdx.x;       // 0..1023
    int d = threadIdx.x;      // 0..255
    ET[k * 256 + d] = E[d * 1024 + k];
}

// ---------------- kernel 2: distance GEMM + argmin ----------------
// Per block: 64 rows x all 1024 codes. Tiles: BN=128 codes, Kd=32.
// 256 threads = 16 tx (code groups of 8) x 16 ty (row groups of 4).
__global__ __launch_bounds__(256) void dist_argmin_kernel(const float* __restrict__ z,
                                                          const float* __restrict__ E,
                                                          const float* __restrict__ colnorm,
                                                          int* __restrict__ idxOut) {
    __shared__ float As[64 * 36];    // [row][dd], padded stride 36 (16B-aligned rows)
    __shared__ float Bs[32 * 128];   // [dd][code]
    __shared__ float bestV[64];
    __shared__ int bestI[64];

    const int t = threadIdx.x;
    const int tx = t & 15;
    const int ty = t >> 4;
    const int r0 = ty * 4;
    const int rowBase = blockIdx.x * 64;

    if (t < 64) { bestV[t] = FLT_MAX; bestI[t] = 0; }

    for (int cb = 0; cb < 8; ++cb) {
        const int cBase = cb * 128;
        float acc[4][8];
#pragma unroll
        for (int i = 0; i < 4; ++i)
#pragma unroll
            for (int j = 0; j < 8; ++j) acc[i][j] = 0.f;

        for (int dc = 0; dc < 8; ++dc) {
            __syncthreads();
            // stage A tile: 64 rows x 32 dd (coalesced float4 x2 per thread)
            {
                int rr = t >> 2;           // 0..63
                int dd = (t & 3) * 8;      // 0,8,16,24
                const float4* g = (const float4*)(z + (size_t)(rowBase + rr) * 256 + dc * 32 + dd);
                float4 v0 = g[0];
                float4 v1 = g[1];
                *(float4*)&As[rr * 36 + dd] = v0;
                *(float4*)&As[rr * 36 + dd + 4] = v1;
            }
            // stage B tile: 32 dd x 128 codes (coalesced float4 x4 per thread)
#pragma unroll
            for (int i = 0; i < 4; ++i) {
                int q = t + 256 * i;       // 0..1023
                int dd = q >> 5;           // 0..31
                int cc = (q & 31) * 4;     // 0..124
                *(float4*)&Bs[dd * 128 + cc] =
                    *(const float4*)(E + (size_t)(dc * 32 + dd) * 1024 + cBase + cc);
            }
            __syncthreads();

#pragma unroll
            for (int dd4 = 0; dd4 < 8; ++dd4) {
                float4 a[4];
#pragma unroll
                for (int i = 0; i < 4; ++i)
                    a[i] = *(const float4*)&As[(r0 + i) * 36 + dd4 * 4];
#pragma unroll
                for (int dd = 0; dd < 4; ++dd) {
                    const float* brow = &Bs[(dd4 * 4 + dd) * 128 + tx * 8];
                    float4 b0 = *(const float4*)brow;
                    float4 b1 = *(const float4*)(brow + 4);
#pragma unroll
                    for (int i = 0; i < 4; ++i) {
                        float av = (dd == 0) ? a[i].x : (dd == 1) ? a[i].y
                                 : (dd == 2) ? a[i].z : a[i].w;
                        acc[i][0] += av * b0.x;
                        acc[i][1] += av * b0.y;
                        acc[i][2] += av * b0.z;
                        acc[i][3] += av * b0.w;
                        acc[i][4] += av * b1.x;
                        acc[i][5] += av * b1.y;
                        acc[i][6] += av * b1.z;
                        acc[i][7] += av * b1.w;
                    }
                }
            }
        }

        // argmin over this 128-code chunk: dist = colnorm[c] - 2*dot  (||z||^2 omitted)
        float cn[8];
        {
            float4 c0 = *(const float4*)&colnorm[cBase + tx * 8];
            float4 c1 = *(const float4*)&colnorm[cBase + tx * 8 + 4];
            cn[0] = c0.x; cn[1] = c0.y; cn[2] = c0.z; cn[3] = c0.w;
            cn[4] = c1.x; cn[5] = c1.y; cn[6] = c1.z; cn[7] = c1.w;
        }
#pragma unroll
        for (int i = 0; i < 4; ++i) {
            float v = FLT_MAX;
            int ci = 0;
#pragma unroll
            for (int j = 0; j < 8; ++j) {
                float dv = cn[j] - 2.f * acc[i][j];
                int cidx = cBase + tx * 8 + j;
                if (dv < v) { v = dv; ci = cidx; }   // strict <: lowest index on tie
            }
            // reduce across the 16 tx lanes (contiguous within the wave)
#pragma unroll
            for (int o = 8; o > 0; o >>= 1) {
                float v2 = __shfl_down(v, o, 64);
                int i2 = __shfl_down(ci, o, 64);
                if (v2 < v || (v2 == v && i2 < ci)) { v = v2; ci = i2; }
            }
            if (tx == 0) {
                int r = r0 + i;
                if (v < bestV[r]) { bestV[r] = v; bestI[r] = ci; }  // strict <: earlier chunk wins tie
            }
        }
    }
    __syncthreads();
    if (t < 64) idxOut[rowBase + t] = bestI[t];
}

// ---------------- kernel 3: gather z_q, loss, scatter counts/embed_sum ----------------
// block=256 threads = 4 waves; each wave handles one row per iteration (64 lanes x float4 = 256 d)
__global__ __launch_bounds__(256) void gather_scatter_kernel(const float* __restrict__ z,
                                                             const float* __restrict__ ET,
                                                             const int* __restrict__ idx,
                                                             float* __restrict__ out0,
                                                             float* __restrict__ esT,
                                                             int* __restrict__ counts,
                                                             float* __restrict__ lossSum) {
    const int t = threadIdx.x;
    const int lane = t & 63;
    const int wv = t >> 6;
    float lacc = 0.f;
    for (int g = blockIdx.x; g < 16384; g += gridDim.x) {
        int row = g * 4 + wv;
        int k = idx[row];
        int d = lane * 4;
        float4 zv = *(const float4*)(z + (size_t)row * 256 + d);
        float4 qv = *(const float4*)(ET + (size_t)k * 256 + d);
        *(float4*)(out0 + (size_t)row * 256 + d) = qv;
        float dx = zv.x - qv.x, dy = zv.y - qv.y, dzv = zv.z - qv.z, dw = zv.w - qv.w;
        lacc += dx * dx + dy * dy + dzv * dzv + dw * dw;
        float* ep = esT + (size_t)k * 256 + d;
        atomicAdd(ep + 0, zv.x);
        atomicAdd(ep + 1, zv.y);
        atomicAdd(ep + 2, zv.z);
        atomicAdd(ep + 3, zv.w);
        if (lane == 0) atomicAdd(counts + k, 1);
    }
#pragma unroll
    for (int o = 32; o > 0; o >>= 1) lacc += __shfl_down(lacc, o, 64);
    __shared__ float sbuf[4];
    if (lane == 0) sbuf[wv] = lacc;
    __syncthreads();
    if (t == 0) atomicAdd(lossSum, sbuf[0] + sbuf[1] + sbuf[2] + sbuf[3]);
}

// ---------------- kernel 4a: cluster_size_new + n + loss finalize ----------------
__global__ __launch_bounds__(1024) void csn_kernel(const float* __restrict__ cluster_size,
                                                   const int* __restrict__ counts,
                                                   float* __restrict__ out3,
                                                   float* __restrict__ out1,
                                                   const float* __restrict__ lossSum,
                                                   float* __restrict__ nOut) {
    int k = threadIdx.x;  // 0..1023
    float cn = cluster_size[k] * DECAYC + (1.f - DECAYC) * (float)counts[k];
    out3[k] = cn;
    float v = cn;
#pragma unroll
    for (int o = 32; o > 0; o >>= 1) v += __shfl_down(v, o, 64);
    __shared__ float sbuf[16];
    int lane = k & 63, wv = k >> 6;
    if (lane == 0) sbuf[wv] = v;
    __syncthreads();
    if (k == 0) {
        float n = 0.f;
#pragma unroll
        for (int i = 0; i < 16; ++i) n += sbuf[i];
        nOut[0] = n;
        out1[0] = 0.25f * lossSum[0] / 16777216.0f;
    }
}

// ---------------- kernel 4b: embedding_mean_new + embedding_new ----------------
__global__ __launch_bounds__(256) void final_kernel(const float* __restrict__ embedding_mean,
                                                    const float* __restrict__ esT,
                                                    const float* __restrict__ csn,
                                                    const float* __restrict__ nPtr,
                                                    float* __restrict__ out2,
                                                    float* __restrict__ out4) {
    int tid = blockIdx.x * 256 + threadIdx.x;  // 0..262143
    int d = tid >> 10;
    int k = tid & 1023;
    float es = esT[(size_t)k * 256 + d];
    float emn = embedding_mean[tid] * DECAYC + (1.f - DECAYC) * es;
    out4[tid] = emn;
    float n = nPtr[0];
    float c = csn[k];
    float cs = (c + EPSQ) / (n + 1024.f * EPSQ) * n;
    out2[tid] = emn / cs;
}

extern "C" void kernel_launch(void* const* d_in, const int* in_sizes, int n_in,
                              void* d_out, int out_size, void* d_ws, size_t ws_size,
                              hipStream_t stream) {
    const float* z = (const float*)d_in[0];
    const float* E = (const float*)d_in[1];
    const float* cluster_size = (const float*)d_in[2];
    const float* embedding_mean = (const float*)d_in[3];

    float* out0 = (float*)d_out;        // z_q_st: 16777216
    float* out1 = out0 + 16777216;      // vq_loss: 1
    float* out2 = out1 + 1;             // embedding_new: 262144
    float* out3 = out2 + 262144;        // cluster_size_new: 1024
    float* out4 = out3 + 1024;          // embedding_mean_new: 262144

    // ws layout (floats):
    float* ws = (float*)d_ws;
    float* colnorm = ws;                 // 1024
    int* idx = (int*)(ws + 1024);        // 65536 ints
    int* counts = (int*)(ws + 66560);    // 1024 ints        (zeroed)
    float* esT = ws + 67584;             // 262144 [k][d]    (zeroed)
    float* lossSum = ws + 329728;        // 1                (zeroed)
    float* nOut = ws + 329729;           // 1
    float* ET = ws + 329732;             // 262144 [k][d], 16B aligned

    // zero counts + esT + lossSum in one contiguous memset
    hipMemsetAsync(counts, 0, (size_t)(1024 + 262144 + 1) * sizeof(float), stream);

    colnorm_kernel<<<4, 256, 0, stream>>>(E, colnorm);
    transpose_kernel<<<1024, 256, 0, stream>>>(E, ET);
    dist_argmin_kernel<<<1024, 256, 0, stream>>>(z, E, colnorm, idx);
    gather_scatter_kernel<<<4096, 256, 0, stream>>>(z, ET, idx, out0, esT, counts, lossSum);
    csn_kernel<<<1, 1024, 0, stream>>>(cluster_size, counts, out3, out1, lossSum, nOut);
    final_kernel<<<1024, 256, 0, stream>>>(embedding_mean, esT, out3, nOut, out2, out4);
}

// Round 3
// 754.635 us; speedup vs baseline: 1.3135x; 1.3135x over previous
//
#include <hip/hip_runtime.h>
#include <cfloat>

// z: [16,4096,256] fp32 -> N=65536 rows, d=256
// embedding: [256,1024], cluster_size: [1024], embedding_mean: [256,1024]
// outputs: z_q_st[16777216], vq_loss[1], embedding_new[262144],
//          cluster_size_new[1024], embedding_mean_new[262144]

#define DECAYC 0.99f
#define EPSQ 1e-5f

typedef unsigned short ushort_t;
typedef __attribute__((ext_vector_type(8))) short bf16x8;
typedef __attribute__((ext_vector_type(4))) float f32x4;

__device__ __forceinline__ ushort_t f2bf(float x) {
    unsigned u = __float_as_uint(x);
    unsigned r = (u + 0x7FFFu + ((u >> 16) & 1u)) >> 16;   // RNE
    return (ushort_t)r;
}
__device__ __forceinline__ float bf2f(ushort_t h) {
    return __uint_as_float(((unsigned)h) << 16);
}
__device__ __forceinline__ unsigned long long umin64(unsigned long long a, unsigned long long b) {
    return a < b ? a : b;
}
__device__ __forceinline__ void async_cp16(const void* g, void* l) {
    __builtin_amdgcn_global_load_lds(
        (const __attribute__((address_space(1))) void*)g,
        (__attribute__((address_space(3))) void*)l, 16, 0, 0);
}

// ---------------- colnorm[k] = sum_d E[d][k]^2 (fp32 exact-ish) ----------------
__global__ __launch_bounds__(256) void colnorm_kernel(const float* __restrict__ E,
                                                      float* __restrict__ colnorm) {
    int k = blockIdx.x * 256 + threadIdx.x;
    float s = 0.f;
#pragma unroll 8
    for (int d = 0; d < 256; ++d) {
        float v = E[d * 1024 + k];
        s += v * v;
    }
    colnorm[k] = s;
}

// ---------------- ET[k][d] = E[d][k] (fp32, for exact z_q gather) ----------------
__global__ __launch_bounds__(256) void transpose_kernel(const float* __restrict__ E,
                                                        float* __restrict__ ET) {
    int k = blockIdx.x;
    int d = threadIdx.x;
    ET[k * 256 + d] = E[d * 1024 + k];
}

// ---------------- prep: z -> zh,zl (bf16 hi/lo, row-major) ----------------
__global__ __launch_bounds__(256) void prep_z_kernel(const float* __restrict__ z,
                                                     ushort_t* __restrict__ zh,
                                                     ushort_t* __restrict__ zl) {
    int tid = blockIdx.x * 256 + threadIdx.x;   // 0..4194303, 4 elems each
    int i4 = tid * 4;
    float4 v = *(const float4*)(z + i4);
    ushort4 h, l;
    h.x = f2bf(v.x); l.x = f2bf(v.x - bf2f(h.x));
    h.y = f2bf(v.y); l.y = f2bf(v.y - bf2f(h.y));
    h.z = f2bf(v.z); l.z = f2bf(v.z - bf2f(h.z));
    h.w = f2bf(v.w); l.w = f2bf(v.w - bf2f(h.w));
    *(ushort4*)(zh + i4) = h;
    *(ushort4*)(zl + i4) = l;
}

// ---------------- prep: E -> Eph,Epl fragment-packed ----------------
// Epack[(kq*1024 + n)*8 + j] = bf16(E[(kq*8+j)*1024 + n]),  kq=0..31, n=0..1023
__global__ __launch_bounds__(256) void prep_E_kernel(const float* __restrict__ E,
                                                     ushort_t* __restrict__ Eph,
                                                     ushort_t* __restrict__ Epl) {
    int t = blockIdx.x * 256 + threadIdx.x;   // 0..32767
    int kq = t >> 10;
    int n = t & 1023;
    ushort4 h0, h1, l0, l1;
    float v;
    v = E[(kq * 8 + 0) * 1024 + n]; h0.x = f2bf(v); l0.x = f2bf(v - bf2f(h0.x));
    v = E[(kq * 8 + 1) * 1024 + n]; h0.y = f2bf(v); l0.y = f2bf(v - bf2f(h0.y));
    v = E[(kq * 8 + 2) * 1024 + n]; h0.z = f2bf(v); l0.z = f2bf(v - bf2f(h0.z));
    v = E[(kq * 8 + 3) * 1024 + n]; h0.w = f2bf(v); l0.w = f2bf(v - bf2f(h0.w));
    v = E[(kq * 8 + 4) * 1024 + n]; h1.x = f2bf(v); l1.x = f2bf(v - bf2f(h1.x));
    v = E[(kq * 8 + 5) * 1024 + n]; h1.y = f2bf(v); l1.y = f2bf(v - bf2f(h1.y));
    v = E[(kq * 8 + 6) * 1024 + n]; h1.z = f2bf(v); l1.z = f2bf(v - bf2f(h1.z));
    v = E[(kq * 8 + 7) * 1024 + n]; h1.w = f2bf(v); l1.w = f2bf(v - bf2f(h1.w));
    *(ushort4*)(Eph + t * 8) = h0;
    *(ushort4*)(Eph + t * 8 + 4) = h1;
    *(ushort4*)(Epl + t * 8) = l0;
    *(ushort4*)(Epl + t * 8 + 4) = l1;
}

// ---------------- MFMA distance + argmin ----------------
// Block: 128 rows x 1024 codes (8 chunks of 128). 256 thr = 4 waves (2x2 of 64x64).
// Split-bf16: acc += Ah*Bh + Ah*Bl + Al*Bh  (lo*lo dropped, ~2^-18 rel).
__global__ __launch_bounds__(256) void dist_mfma_kernel(const ushort_t* __restrict__ zh,
                                                        const ushort_t* __restrict__ zl,
                                                        const ushort_t* __restrict__ Eph,
                                                        const ushort_t* __restrict__ Epl,
                                                        const float* __restrict__ colnorm,
                                                        int* __restrict__ idxOut) {
    // fragment-ordered LDS: slot s = q*128 + r ; 16 B per slot
    __shared__ __align__(16) ushort_t Ah[4096], Al[4096], Bh[4096], Bl[4096];
    __shared__ unsigned long long bestKey[2][128];

    const int t = threadIdx.x;
    const int lane = t & 63;
    const int w = t >> 6;         // wave 0..3
    const int wrow = w >> 1;      // 0..1 (rows 64*wrow..)
    const int wcol = w & 1;       // 0..1 (codes 64*wcol..)
    const int n16 = lane & 15;
    const int q = lane >> 4;      // 0..3
    const int rowBase = blockIdx.x * 128;

    bestKey[t >> 7][t & 127] = ~0ull;

    // two staging instructions per wave per array
    const int s0 = (w * 2 + 0) * 64 + lane;
    const int s1 = (w * 2 + 1) * 64 + lane;
    const int q0 = s0 >> 7, r0 = s0 & 127;
    const int q1 = s1 >> 7, r1 = s1 & 127;
    const int ldsOff0 = (w * 2 + 0) * 512;   // ushort units (=1024 B)
    const int ldsOff1 = (w * 2 + 1) * 512;

    for (int cb = 0; cb < 8; ++cb) {
        const int cBase = cb * 128;
        f32x4 acc[4][4];
#pragma unroll
        for (int i = 0; i < 4; ++i)
#pragma unroll
            for (int j = 0; j < 4; ++j) acc[i][j] = (f32x4){0.f, 0.f, 0.f, 0.f};

        for (int ks = 0; ks < 8; ++ks) {
            __syncthreads();   // previous iter's frag reads done
            // A tiles: LDS[(q*128+r)*8] <- zh[(rowBase+r)*256 + ks*32 + q*8]
            async_cp16(zh + (size_t)(rowBase + r0) * 256 + ks * 32 + q0 * 8, Ah + ldsOff0);
            async_cp16(zh + (size_t)(rowBase + r1) * 256 + ks * 32 + q1 * 8, Ah + ldsOff1);
            async_cp16(zl + (size_t)(rowBase + r0) * 256 + ks * 32 + q0 * 8, Al + ldsOff0);
            async_cp16(zl + (size_t)(rowBase + r1) * 256 + ks * 32 + q1 * 8, Al + ldsOff1);
            // B tiles: LDS[(q*128+c)*8] <- Epack[((ks*4+q)*1024 + cBase + c)*8]
            async_cp16(Eph + ((size_t)(ks * 4 + q0) * 1024 + cBase + r0) * 8, Bh + ldsOff0);
            async_cp16(Eph + ((size_t)(ks * 4 + q1) * 1024 + cBase + r1) * 8, Bh + ldsOff1);
            async_cp16(Epl + ((size_t)(ks * 4 + q0) * 1024 + cBase + r0) * 8, Bl + ldsOff0);
            async_cp16(Epl + ((size_t)(ks * 4 + q1) * 1024 + cBase + r1) * 8, Bl + ldsOff1);
            __syncthreads();   // staging visible (syncthreads drains vmcnt)

            const int aoff = (q * 128 + wrow * 64 + n16) * 8;
            const int boff = (q * 128 + wcol * 64 + n16) * 8;
            bf16x8 afh[4], afl[4], bfh[4], bfl[4];
#pragma unroll
            for (int rt = 0; rt < 4; ++rt) {
                afh[rt] = *(const bf16x8*)&Ah[aoff + rt * 128];
                afl[rt] = *(const bf16x8*)&Al[aoff + rt * 128];
            }
#pragma unroll
            for (int ct = 0; ct < 4; ++ct) {
                bfh[ct] = *(const bf16x8*)&Bh[boff + ct * 128];
                bfl[ct] = *(const bf16x8*)&Bl[boff + ct * 128];
            }
#pragma unroll
            for (int rt = 0; rt < 4; ++rt)
#pragma unroll
                for (int ct = 0; ct < 4; ++ct) {
                    acc[rt][ct] = __builtin_amdgcn_mfma_f32_16x16x32_bf16(afh[rt], bfh[ct], acc[rt][ct], 0, 0, 0);
                    acc[rt][ct] = __builtin_amdgcn_mfma_f32_16x16x32_bf16(afh[rt], bfl[ct], acc[rt][ct], 0, 0, 0);
                    acc[rt][ct] = __builtin_amdgcn_mfma_f32_16x16x32_bf16(afl[rt], bfh[ct], acc[rt][ct], 0, 0, 0);
                }
        }

        // argmin over this 128-code chunk. C layout: row=q*4+reg, col=n16.
        float cn[4];
#pragma unroll
        for (int ct = 0; ct < 4; ++ct) cn[ct] = colnorm[cBase + wcol * 64 + ct * 16 + n16];
#pragma unroll
        for (int rt = 0; rt < 4; ++rt)
#pragma unroll
            for (int reg = 0; reg < 4; ++reg) {
                unsigned long long best = ~0ull;
#pragma unroll
                for (int ct = 0; ct < 4; ++ct) {
                    float dist = cn[ct] - 2.f * acc[rt][ct][reg];
                    unsigned fb = __float_as_uint(dist);
                    unsigned sk = (fb & 0x80000000u) ? ~fb : (fb | 0x80000000u);
                    unsigned code = (unsigned)(cBase + wcol * 64 + ct * 16 + n16);
                    best = umin64(best, ((unsigned long long)sk << 32) | code);
                }
                best = umin64(best, __shfl_xor(best, 1, 64));
                best = umin64(best, __shfl_xor(best, 2, 64));
                best = umin64(best, __shfl_xor(best, 4, 64));
                best = umin64(best, __shfl_xor(best, 8, 64));
                if (n16 == 0) {
                    int rl = wrow * 64 + rt * 16 + q * 4 + reg;
                    if (best < bestKey[wcol][rl]) bestKey[wcol][rl] = best;
                }
            }
    }
    __syncthreads();
    if (t < 128) {
        unsigned long long k = umin64(bestKey[0][t], bestKey[1][t]);
        idxOut[rowBase + t] = (int)(unsigned)(k & 0xFFFFFFFFull);
    }
}

// ---------------- fp32 fallback distance+argmin (proven, round-2) ----------------
__global__ __launch_bounds__(256) void dist_argmin_kernel(const float* __restrict__ z,
                                                          const float* __restrict__ E,
                                                          const float* __restrict__ colnorm,
                                                          int* __restrict__ idxOut) {
    __shared__ float As[64 * 36];
    __shared__ float Bs[32 * 128];
    __shared__ float bestV[64];
    __shared__ int bestI[64];
    const int t = threadIdx.x;
    const int tx = t & 15;
    const int ty = t >> 4;
    const int r0 = ty * 4;
    const int rowBase = blockIdx.x * 64;
    if (t < 64) { bestV[t] = FLT_MAX; bestI[t] = 0; }
    for (int cb = 0; cb < 8; ++cb) {
        const int cBase = cb * 128;
        float acc[4][8];
#pragma unroll
        for (int i = 0; i < 4; ++i)
#pragma unroll
            for (int j = 0; j < 8; ++j) acc[i][j] = 0.f;
        for (int dc = 0; dc < 8; ++dc) {
            __syncthreads();
            {
                int rr = t >> 2;
                int dd = (t & 3) * 8;
                const float4* g = (const float4*)(z + (size_t)(rowBase + rr) * 256 + dc * 32 + dd);
                float4 v0 = g[0];
                float4 v1 = g[1];
                *(float4*)&As[rr * 36 + dd] = v0;
                *(float4*)&As[rr * 36 + dd + 4] = v1;
            }
#pragma unroll
            for (int i = 0; i < 4; ++i) {
                int qq = t + 256 * i;
                int dd = qq >> 5;
                int cc = (qq & 31) * 4;
                *(float4*)&Bs[dd * 128 + cc] =
                    *(const float4*)(E + (size_t)(dc * 32 + dd) * 1024 + cBase + cc);
            }
            __syncthreads();
#pragma unroll
            for (int dd4 = 0; dd4 < 8; ++dd4) {
                float4 a[4];
#pragma unroll
                for (int i = 0; i < 4; ++i)
                    a[i] = *(const float4*)&As[(r0 + i) * 36 + dd4 * 4];
#pragma unroll
                for (int dd = 0; dd < 4; ++dd) {
                    const float* brow = &Bs[(dd4 * 4 + dd) * 128 + tx * 8];
                    float4 b0 = *(const float4*)brow;
                    float4 b1 = *(const float4*)(brow + 4);
#pragma unroll
                    for (int i = 0; i < 4; ++i) {
                        float av = (dd == 0) ? a[i].x : (dd == 1) ? a[i].y
                                 : (dd == 2) ? a[i].z : a[i].w;
                        acc[i][0] += av * b0.x; acc[i][1] += av * b0.y;
                        acc[i][2] += av * b0.z; acc[i][3] += av * b0.w;
                        acc[i][4] += av * b1.x; acc[i][5] += av * b1.y;
                        acc[i][6] += av * b1.z; acc[i][7] += av * b1.w;
                    }
                }
            }
        }
        float cn[8];
        {
            float4 c0 = *(const float4*)&colnorm[cBase + tx * 8];
            float4 c1 = *(const float4*)&colnorm[cBase + tx * 8 + 4];
            cn[0] = c0.x; cn[1] = c0.y; cn[2] = c0.z; cn[3] = c0.w;
            cn[4] = c1.x; cn[5] = c1.y; cn[6] = c1.z; cn[7] = c1.w;
        }
#pragma unroll
        for (int i = 0; i < 4; ++i) {
            float v = FLT_MAX;
            int ci = 0;
#pragma unroll
            for (int j = 0; j < 8; ++j) {
                float dv = cn[j] - 2.f * acc[i][j];
                int cidx = cBase + tx * 8 + j;
                if (dv < v) { v = dv; ci = cidx; }
            }
#pragma unroll
            for (int o = 8; o > 0; o >>= 1) {
                float v2 = __shfl_down(v, o, 64);
                int i2 = __shfl_down(ci, o, 64);
                if (v2 < v || (v2 == v && i2 < ci)) { v = v2; ci = i2; }
            }
            if (tx == 0) {
                int r = r0 + i;
                if (v < bestV[r]) { bestV[r] = v; bestI[r] = ci; }
            }
        }
    }
    __syncthreads();
    if (t < 64) idxOut[rowBase + t] = bestI[t];
}

// ---------------- gather z_q, loss, scatter counts/embed_sum ----------------
__global__ __launch_bounds__(256) void gather_scatter_kernel(const float* __restrict__ z,
                                                             const float* __restrict__ ET,
                                                             const int* __restrict__ idx,
                                                             float* __restrict__ out0,
                                                             float* __restrict__ esT,
                                                             int* __restrict__ counts,
                                                             float* __restrict__ lossSum) {
    const int t = threadIdx.x;
    const int lane = t & 63;
    const int wv = t >> 6;
    float lacc = 0.f;
    for (int g = blockIdx.x; g < 16384; g += gridDim.x) {
        int row = g * 4 + wv;
        int k = idx[row];
        int d = lane * 4;
        float4 zv = *(const float4*)(z + (size_t)row * 256 + d);
        float4 qv = *(const float4*)(ET + (size_t)k * 256 + d);
        *(float4*)(out0 + (size_t)row * 256 + d) = qv;
        float dx = zv.x - qv.x, dy = zv.y - qv.y, dzv = zv.z - qv.z, dw = zv.w - qv.w;
        lacc += dx * dx + dy * dy + dzv * dzv + dw * dw;
        float* ep = esT + (size_t)k * 256 + d;
        atomicAdd(ep + 0, zv.x);
        atomicAdd(ep + 1, zv.y);
        atomicAdd(ep + 2, zv.z);
        atomicAdd(ep + 3, zv.w);
        if (lane == 0) atomicAdd(counts + k, 1);
    }
#pragma unroll
    for (int o = 32; o > 0; o >>= 1) lacc += __shfl_down(lacc, o, 64);
    __shared__ float sbuf[4];
    if (lane == 0) sbuf[wv] = lacc;
    __syncthreads();
    if (t == 0) atomicAdd(lossSum, sbuf[0] + sbuf[1] + sbuf[2] + sbuf[3]);
}

// ---------------- cluster_size_new + n + loss finalize ----------------
__global__ __launch_bounds__(1024) void csn_kernel(const float* __restrict__ cluster_size,
                                                   const int* __restrict__ counts,
                                                   float* __restrict__ out3,
                                                   float* __restrict__ out1,
                                                   const float* __restrict__ lossSum,
                                                   float* __restrict__ nOut) {
    int k = threadIdx.x;
    float cn = cluster_size[k] * DECAYC + (1.f - DECAYC) * (float)counts[k];
    out3[k] = cn;
    float v = cn;
#pragma unroll
    for (int o = 32; o > 0; o >>= 1) v += __shfl_down(v, o, 64);
    __shared__ float sbuf[16];
    int lane = k & 63, wv = k >> 6;
    if (lane == 0) sbuf[wv] = v;
    __syncthreads();
    if (k == 0) {
        float n = 0.f;
#pragma unroll
        for (int i = 0; i < 16; ++i) n += sbuf[i];
        nOut[0] = n;
        out1[0] = 0.25f * lossSum[0] / 16777216.0f;
    }
}

// ---------------- embedding_mean_new + embedding_new ----------------
__global__ __launch_bounds__(256) void final_kernel(const float* __restrict__ embedding_mean,
                                                    const float* __restrict__ esT,
                                                    const float* __restrict__ csn,
                                                    const float* __restrict__ nPtr,
                                                    float* __restrict__ out2,
                                                    float* __restrict__ out4) {
    int tid = blockIdx.x * 256 + threadIdx.x;
    int d = tid >> 10;
    int k = tid & 1023;
    float es = esT[(size_t)k * 256 + d];
    float emn = embedding_mean[tid] * DECAYC + (1.f - DECAYC) * es;
    out4[tid] = emn;
    float n = nPtr[0];
    float c = csn[k];
    float cs = (c + EPSQ) / (n + 1024.f * EPSQ) * n;
    out2[tid] = emn / cs;
}

extern "C" void kernel_launch(void* const* d_in, const int* in_sizes, int n_in,
                              void* d_out, int out_size, void* d_ws, size_t ws_size,
                              hipStream_t stream) {
    const float* z = (const float*)d_in[0];
    const float* E = (const float*)d_in[1];
    const float* cluster_size = (const float*)d_in[2];
    const float* embedding_mean = (const float*)d_in[3];

    float* out0 = (float*)d_out;        // z_q_st
    float* out1 = out0 + 16777216;      // vq_loss
    float* out2 = out1 + 1;             // embedding_new
    float* out3 = out2 + 262144;        // cluster_size_new
    float* out4 = out3 + 1024;          // embedding_mean_new

    // ws layout (float units)
    float* ws = (float*)d_ws;
    float* colnorm = ws;                         // 1024
    int* idx = (int*)(ws + 1024);                // 65536
    int* counts = (int*)(ws + 66560);            // 1024   (zeroed)
    float* esT = ws + 67584;                     // 262144 (zeroed)
    float* lossSum = ws + 329728;                // 1      (zeroed)
    float* nOut = ws + 329729;                   // 1
    float* ET = ws + 329732;                     // 262144 fp32 [k][d]
    ushort_t* zh = (ushort_t*)(ws + 591876);     // 16777216 bf16
    ushort_t* zl = (ushort_t*)(ws + 8980484);    // 16777216 bf16
    ushort_t* Eph = (ushort_t*)(ws + 17369092);  // 262144 bf16 packed
    ushort_t* Epl = (ushort_t*)(ws + 17500164);  // 262144 bf16 packed
    const size_t needed = 17631236ull * 4ull;    // ~70.5 MB

    hipMemsetAsync(counts, 0, (size_t)(1024 + 262144 + 1) * sizeof(float), stream);

    colnorm_kernel<<<4, 256, 0, stream>>>(E, colnorm);
    transpose_kernel<<<1024, 256, 0, stream>>>(E, ET);

    if (ws_size >= needed) {
        prep_z_kernel<<<16384, 256, 0, stream>>>(z, zh, zl);
        prep_E_kernel<<<128, 256, 0, stream>>>(E, Eph, Epl);
        dist_mfma_kernel<<<512, 256, 0, stream>>>(zh, zl, Eph, Epl, colnorm, idx);
    } else {
        dist_argmin_kernel<<<1024, 256, 0, stream>>>(z, E, colnorm, idx);
    }

    gather_scatter_kernel<<<4096, 256, 0, stream>>>(z, ET, idx, out0, esT, counts, lossSum);
    csn_kernel<<<1, 1024, 0, stream>>>(cluster_size, counts, out3, out1, lossSum, nOut);
    final_kernel<<<1024, 256, 0, stream>>>(embedding_mean, esT, out3, nOut, out2, out4);
}

// Round 4
// 519.493 us; speedup vs baseline: 1.9081x; 1.4526x over previous
//
#include <hip/hip_runtime.h>
#include <cfloat>

// z: [16,4096,256] fp32 -> N=65536 rows, d=256
// embedding: [256,1024], cluster_size: [1024], embedding_mean: [256,1024]
// outputs: z_q_st[16777216], vq_loss[1], embedding_new[262144],
//          cluster_size_new[1024], embedding_mean_new[262144]

#define DECAYC 0.99f
#define EPSQ 1e-5f

typedef unsigned short ushort_t;
typedef __attribute__((ext_vector_type(8))) short bf16x8;
typedef __attribute__((ext_vector_type(4))) float f32x4;

__device__ __forceinline__ ushort_t f2bf(float x) {
    unsigned u = __float_as_uint(x);
    unsigned r = (u + 0x7FFFu + ((u >> 16) & 1u)) >> 16;   // RNE
    return (ushort_t)r;
}
__device__ __forceinline__ float bf2f(ushort_t h) {
    return __uint_as_float(((unsigned)h) << 16);
}
__device__ __forceinline__ unsigned long long umin64(unsigned long long a, unsigned long long b) {
    return a < b ? a : b;
}
__device__ __forceinline__ void async_cp16(const void* g, void* l) {
    __builtin_amdgcn_global_load_lds(
        (const __attribute__((address_space(1))) void*)g,
        (__attribute__((address_space(3))) void*)l, 16, 0, 0);
}

// ---------------- colnorm[k] = sum_d E[d][k]^2 ----------------
__global__ __launch_bounds__(256) void colnorm_kernel(const float* __restrict__ E,
                                                      float* __restrict__ colnorm) {
    int k = blockIdx.x * 256 + threadIdx.x;
    float s = 0.f;
#pragma unroll 8
    for (int d = 0; d < 256; ++d) {
        float v = E[d * 1024 + k];
        s += v * v;
    }
    colnorm[k] = s;
}

// ---------------- ET[k][d] = E[d][k] ----------------
__global__ __launch_bounds__(256) void transpose_kernel(const float* __restrict__ E,
                                                        float* __restrict__ ET) {
    int k = blockIdx.x;
    int d = threadIdx.x;
    ET[k * 256 + d] = E[d * 1024 + k];
}

// ---------------- prep: z -> zh,zl (bf16 hi/lo, row-major) ----------------
__global__ __launch_bounds__(256) void prep_z_kernel(const float* __restrict__ z,
                                                     ushort_t* __restrict__ zh,
                                                     ushort_t* __restrict__ zl) {
    int tid = blockIdx.x * 256 + threadIdx.x;
    int i4 = tid * 4;
    float4 v = *(const float4*)(z + i4);
    ushort4 h, l;
    h.x = f2bf(v.x); l.x = f2bf(v.x - bf2f(h.x));
    h.y = f2bf(v.y); l.y = f2bf(v.y - bf2f(h.y));
    h.z = f2bf(v.z); l.z = f2bf(v.z - bf2f(h.z));
    h.w = f2bf(v.w); l.w = f2bf(v.w - bf2f(h.w));
    *(ushort4*)(zh + i4) = h;
    *(ushort4*)(zl + i4) = l;
}

// ---------------- prep: E -> Eph,Epl fragment-packed ----------------
__global__ __launch_bounds__(256) void prep_E_kernel(const float* __restrict__ E,
                                                     ushort_t* __restrict__ Eph,
                                                     ushort_t* __restrict__ Epl) {
    int t = blockIdx.x * 256 + threadIdx.x;   // 0..32767
    int kq = t >> 10;
    int n = t & 1023;
    ushort4 h0, h1, l0, l1;
    float v;
    v = E[(kq * 8 + 0) * 1024 + n]; h0.x = f2bf(v); l0.x = f2bf(v - bf2f(h0.x));
    v = E[(kq * 8 + 1) * 1024 + n]; h0.y = f2bf(v); l0.y = f2bf(v - bf2f(h0.y));
    v = E[(kq * 8 + 2) * 1024 + n]; h0.z = f2bf(v); l0.z = f2bf(v - bf2f(h0.z));
    v = E[(kq * 8 + 3) * 1024 + n]; h0.w = f2bf(v); l0.w = f2bf(v - bf2f(h0.w));
    v = E[(kq * 8 + 4) * 1024 + n]; h1.x = f2bf(v); l1.x = f2bf(v - bf2f(h1.x));
    v = E[(kq * 8 + 5) * 1024 + n]; h1.y = f2bf(v); l1.y = f2bf(v - bf2f(h1.y));
    v = E[(kq * 8 + 6) * 1024 + n]; h1.z = f2bf(v); l1.z = f2bf(v - bf2f(h1.z));
    v = E[(kq * 8 + 7) * 1024 + n]; h1.w = f2bf(v); l1.w = f2bf(v - bf2f(h1.w));
    *(ushort4*)(Eph + t * 8) = h0;
    *(ushort4*)(Eph + t * 8 + 4) = h1;
    *(ushort4*)(Epl + t * 8) = l0;
    *(ushort4*)(Epl + t * 8 + 4) = l1;
}

// ---------------- MFMA distance + argmin ----------------
__global__ __launch_bounds__(256) void dist_mfma_kernel(const ushort_t* __restrict__ zh,
                                                        const ushort_t* __restrict__ zl,
                                                        const ushort_t* __restrict__ Eph,
                                                        const ushort_t* __restrict__ Epl,
                                                        const float* __restrict__ colnorm,
                                                        int* __restrict__ idxOut) {
    __shared__ __align__(16) ushort_t Ah[4096], Al[4096], Bh[4096], Bl[4096];
    __shared__ unsigned long long bestKey[2][128];

    const int t = threadIdx.x;
    const int lane = t & 63;
    const int w = t >> 6;
    const int wrow = w >> 1;
    const int wcol = w & 1;
    const int n16 = lane & 15;
    const int q = lane >> 4;
    const int rowBase = blockIdx.x * 128;

    bestKey[t >> 7][t & 127] = ~0ull;

    const int s0 = (w * 2 + 0) * 64 + lane;
    const int s1 = (w * 2 + 1) * 64 + lane;
    const int q0 = s0 >> 7, r0 = s0 & 127;
    const int q1 = s1 >> 7, r1 = s1 & 127;
    const int ldsOff0 = (w * 2 + 0) * 512;
    const int ldsOff1 = (w * 2 + 1) * 512;

    for (int cb = 0; cb < 8; ++cb) {
        const int cBase = cb * 128;
        f32x4 acc[4][4];
#pragma unroll
        for (int i = 0; i < 4; ++i)
#pragma unroll
            for (int j = 0; j < 4; ++j) acc[i][j] = (f32x4){0.f, 0.f, 0.f, 0.f};

        for (int ks = 0; ks < 8; ++ks) {
            __syncthreads();
            async_cp16(zh + (size_t)(rowBase + r0) * 256 + ks * 32 + q0 * 8, Ah + ldsOff0);
            async_cp16(zh + (size_t)(rowBase + r1) * 256 + ks * 32 + q1 * 8, Ah + ldsOff1);
            async_cp16(zl + (size_t)(rowBase + r0) * 256 + ks * 32 + q0 * 8, Al + ldsOff0);
            async_cp16(zl + (size_t)(rowBase + r1) * 256 + ks * 32 + q1 * 8, Al + ldsOff1);
            async_cp16(Eph + ((size_t)(ks * 4 + q0) * 1024 + cBase + r0) * 8, Bh + ldsOff0);
            async_cp16(Eph + ((size_t)(ks * 4 + q1) * 1024 + cBase + r1) * 8, Bh + ldsOff1);
            async_cp16(Epl + ((size_t)(ks * 4 + q0) * 1024 + cBase + r0) * 8, Bl + ldsOff0);
            async_cp16(Epl + ((size_t)(ks * 4 + q1) * 1024 + cBase + r1) * 8, Bl + ldsOff1);
            __syncthreads();

            const int aoff = (q * 128 + wrow * 64 + n16) * 8;
            const int boff = (q * 128 + wcol * 64 + n16) * 8;
            bf16x8 afh[4], afl[4], bfh[4], bfl[4];
#pragma unroll
            for (int rt = 0; rt < 4; ++rt) {
                afh[rt] = *(const bf16x8*)&Ah[aoff + rt * 128];
                afl[rt] = *(const bf16x8*)&Al[aoff + rt * 128];
            }
#pragma unroll
            for (int ct = 0; ct < 4; ++ct) {
                bfh[ct] = *(const bf16x8*)&Bh[boff + ct * 128];
                bfl[ct] = *(const bf16x8*)&Bl[boff + ct * 128];
            }
#pragma unroll
            for (int rt = 0; rt < 4; ++rt)
#pragma unroll
                for (int ct = 0; ct < 4; ++ct) {
                    acc[rt][ct] = __builtin_amdgcn_mfma_f32_16x16x32_bf16(afh[rt], bfh[ct], acc[rt][ct], 0, 0, 0);
                    acc[rt][ct] = __builtin_amdgcn_mfma_f32_16x16x32_bf16(afh[rt], bfl[ct], acc[rt][ct], 0, 0, 0);
                    acc[rt][ct] = __builtin_amdgcn_mfma_f32_16x16x32_bf16(afl[rt], bfh[ct], acc[rt][ct], 0, 0, 0);
                }
        }

        float cn[4];
#pragma unroll
        for (int ct = 0; ct < 4; ++ct) cn[ct] = colnorm[cBase + wcol * 64 + ct * 16 + n16];
#pragma unroll
        for (int rt = 0; rt < 4; ++rt)
#pragma unroll
            for (int reg = 0; reg < 4; ++reg) {
                unsigned long long best = ~0ull;
#pragma unroll
                for (int ct = 0; ct < 4; ++ct) {
                    float dist = cn[ct] - 2.f * acc[rt][ct][reg];
                    unsigned fb = __float_as_uint(dist);
                    unsigned sk = (fb & 0x80000000u) ? ~fb : (fb | 0x80000000u);
                    unsigned code = (unsigned)(cBase + wcol * 64 + ct * 16 + n16);
                    best = umin64(best, ((unsigned long long)sk << 32) | code);
                }
                best = umin64(best, __shfl_xor(best, 1, 64));
                best = umin64(best, __shfl_xor(best, 2, 64));
                best = umin64(best, __shfl_xor(best, 4, 64));
                best = umin64(best, __shfl_xor(best, 8, 64));
                if (n16 == 0) {
                    int rl = wrow * 64 + rt * 16 + q * 4 + reg;
                    if (best < bestKey[wcol][rl]) bestKey[wcol][rl] = best;
                }
            }
    }
    __syncthreads();
    if (t < 128) {
        unsigned long long k = umin64(bestKey[0][t], bestKey[1][t]);
        idxOut[rowBase + t] = (int)(unsigned)(k & 0xFFFFFFFFull);
    }
}

// ---------------- fp32 fallback distance+argmin ----------------
__global__ __launch_bounds__(256) void dist_argmin_kernel(const float* __restrict__ z,
                                                          const float* __restrict__ E,
                                                          const float* __restrict__ colnorm,
                                                          int* __restrict__ idxOut) {
    __shared__ float As[64 * 36];
    __shared__ float Bs[32 * 128];
    __shared__ float bestV[64];
    __shared__ int bestI[64];
    const int t = threadIdx.x;
    const int tx = t & 15;
    const int ty = t >> 4;
    const int r0 = ty * 4;
    const int rowBase = blockIdx.x * 64;
    if (t < 64) { bestV[t] = FLT_MAX; bestI[t] = 0; }
    for (int cb = 0; cb < 8; ++cb) {
        const int cBase = cb * 128;
        float acc[4][8];
#pragma unroll
        for (int i = 0; i < 4; ++i)
#pragma unroll
            for (int j = 0; j < 8; ++j) acc[i][j] = 0.f;
        for (int dc = 0; dc < 8; ++dc) {
            __syncthreads();
            {
                int rr = t >> 2;
                int dd = (t & 3) * 8;
                const float4* g = (const float4*)(z + (size_t)(rowBase + rr) * 256 + dc * 32 + dd);
                float4 v0 = g[0];
                float4 v1 = g[1];
                *(float4*)&As[rr * 36 + dd] = v0;
                *(float4*)&As[rr * 36 + dd + 4] = v1;
            }
#pragma unroll
            for (int i = 0; i < 4; ++i) {
                int qq = t + 256 * i;
                int dd = qq >> 5;
                int cc = (qq & 31) * 4;
                *(float4*)&Bs[dd * 128 + cc] =
                    *(const float4*)(E + (size_t)(dc * 32 + dd) * 1024 + cBase + cc);
            }
            __syncthreads();
#pragma unroll
            for (int dd4 = 0; dd4 < 8; ++dd4) {
                float4 a[4];
#pragma unroll
                for (int i = 0; i < 4; ++i)
                    a[i] = *(const float4*)&As[(r0 + i) * 36 + dd4 * 4];
#pragma unroll
                for (int dd = 0; dd < 4; ++dd) {
                    const float* brow = &Bs[(dd4 * 4 + dd) * 128 + tx * 8];
                    float4 b0 = *(const float4*)brow;
                    float4 b1 = *(const float4*)(brow + 4);
#pragma unroll
                    for (int i = 0; i < 4; ++i) {
                        float av = (dd == 0) ? a[i].x : (dd == 1) ? a[i].y
                                 : (dd == 2) ? a[i].z : a[i].w;
                        acc[i][0] += av * b0.x; acc[i][1] += av * b0.y;
                        acc[i][2] += av * b0.z; acc[i][3] += av * b0.w;
                        acc[i][4] += av * b1.x; acc[i][5] += av * b1.y;
                        acc[i][6] += av * b1.z; acc[i][7] += av * b1.w;
                    }
                }
            }
        }
        float cn[8];
        {
            float4 c0 = *(const float4*)&colnorm[cBase + tx * 8];
            float4 c1 = *(const float4*)&colnorm[cBase + tx * 8 + 4];
            cn[0] = c0.x; cn[1] = c0.y; cn[2] = c0.z; cn[3] = c0.w;
            cn[4] = c1.x; cn[5] = c1.y; cn[6] = c1.z; cn[7] = c1.w;
        }
#pragma unroll
        for (int i = 0; i < 4; ++i) {
            float v = FLT_MAX;
            int ci = 0;
#pragma unroll
            for (int j = 0; j < 8; ++j) {
                float dv = cn[j] - 2.f * acc[i][j];
                int cidx = cBase + tx * 8 + j;
                if (dv < v) { v = dv; ci = cidx; }
            }
#pragma unroll
            for (int o = 8; o > 0; o >>= 1) {
                float v2 = __shfl_down(v, o, 64);
                int i2 = __shfl_down(ci, o, 64);
                if (v2 < v || (v2 == v && i2 < ci)) { v = v2; ci = i2; }
            }
            if (tx == 0) {
                int r = r0 + i;
                if (v < bestV[r]) { bestV[r] = v; bestI[r] = ci; }
            }
        }
    }
    __syncthreads();
    if (t < 64) idxOut[rowBase + t] = bestI[t];
}

// ---------------- gather z_q + loss (NO stats atomics) ----------------
__global__ __launch_bounds__(256) void gather_loss_kernel(const float* __restrict__ z,
                                                          const float* __restrict__ ET,
                                                          const int* __restrict__ idx,
                                                          float* __restrict__ out0,
                                                          float* __restrict__ lossSum) {
    const int t = threadIdx.x;
    const int lane = t & 63;
    const int wv = t >> 6;
    float lacc = 0.f;
    for (int g = blockIdx.x; g < 16384; g += gridDim.x) {
        int row = g * 4 + wv;
        int k = idx[row];
        int d = lane * 4;
        float4 zv = *(const float4*)(z + (size_t)row * 256 + d);
        float4 qv = *(const float4*)(ET + (size_t)k * 256 + d);
        *(float4*)(out0 + (size_t)row * 256 + d) = qv;
        float dx = zv.x - qv.x, dy = zv.y - qv.y, dzv = zv.z - qv.z, dw = zv.w - qv.w;
        lacc += dx * dx + dy * dy + dzv * dzv + dw * dw;
    }
#pragma unroll
    for (int o = 32; o > 0; o >>= 1) lacc += __shfl_down(lacc, o, 64);
    __shared__ float sbuf[4];
    if (lane == 0) sbuf[wv] = lacc;
    __syncthreads();
    if (t == 0) atomicAdd(lossSum, sbuf[0] + sbuf[1] + sbuf[2] + sbuf[3]);
}

// ---------------- histogram (exact int counts) ----------------
__global__ __launch_bounds__(256) void hist_kernel(const int* __restrict__ idx,
                                                   int* __restrict__ counts) {
    int i = blockIdx.x * 256 + threadIdx.x;
    atomicAdd(counts + idx[i], 1);
}

// ---------------- prefix sum over counts + zero cursors ----------------
__global__ __launch_bounds__(1024) void prefix_kernel(const int* __restrict__ counts,
                                                      int* __restrict__ offsets,
                                                      int* __restrict__ cursor) {
    __shared__ int sbuf[1024];
    int t = threadIdx.x;
    int c = counts[t];
    sbuf[t] = c;
    __syncthreads();
    for (int off = 1; off < 1024; off <<= 1) {
        int v = (t >= off) ? sbuf[t - off] : 0;
        __syncthreads();
        sbuf[t] += v;
        __syncthreads();
    }
    offsets[t] = sbuf[t] - c;             // exclusive
    if (t == 1023) offsets[1024] = sbuf[1023];
    cursor[t] = 0;
}

// ---------------- scatter row ids into code-sorted order ----------------
__global__ __launch_bounds__(256) void scatter_sort_kernel(const int* __restrict__ idx,
                                                           const int* __restrict__ offsets,
                                                           int* __restrict__ cursor,
                                                           int* __restrict__ sorted) {
    int i = blockIdx.x * 256 + threadIdx.x;
    int k = idx[i];
    int pos = atomicAdd(cursor + k, 1);
    sorted[offsets[k] + pos] = i;
}

// ---------------- segmented sum: psum[(k*8+s)*256+d] (no atomics) ----------------
__global__ __launch_bounds__(256) void segsum_kernel(const float* __restrict__ z,
                                                     const int* __restrict__ sorted,
                                                     const int* __restrict__ offsets,
                                                     float* __restrict__ psum) {
    const int k = blockIdx.x >> 3;
    const int s = blockIdx.x & 7;
    const int t = threadIdx.x;
    const int lane = t & 63;
    const int w = t >> 6;
    const int start = offsets[k], end = offsets[k + 1];
    float4 acc = {0.f, 0.f, 0.f, 0.f};
    for (int j = start + s * 4 + w; j < end; j += 32) {
        int row = sorted[j];
        float4 v = *(const float4*)(z + (size_t)row * 256 + lane * 4);
        acc.x += v.x; acc.y += v.y; acc.z += v.z; acc.w += v.w;
    }
    __shared__ float red[4][256];
    *(float4*)&red[w][lane * 4] = acc;
    __syncthreads();
    float v = red[0][t] + red[1][t] + red[2][t] + red[3][t];
    psum[((size_t)k * 8 + s) * 256 + t] = v;
}

// ---------------- fallback gather+scatter (fp32 atomics) ----------------
__global__ __launch_bounds__(256) void gather_scatter_kernel(const float* __restrict__ z,
                                                             const float* __restrict__ ET,
                                                             const int* __restrict__ idx,
                                                             float* __restrict__ out0,
                                                             float* __restrict__ esT,
                                                             int* __restrict__ counts,
                                                             float* __restrict__ lossSum) {
    const int t = threadIdx.x;
    const int lane = t & 63;
    const int wv = t >> 6;
    float lacc = 0.f;
    for (int g = blockIdx.x; g < 16384; g += gridDim.x) {
        int row = g * 4 + wv;
        int k = idx[row];
        int d = lane * 4;
        float4 zv = *(const float4*)(z + (size_t)row * 256 + d);
        float4 qv = *(const float4*)(ET + (size_t)k * 256 + d);
        *(float4*)(out0 + (size_t)row * 256 + d) = qv;
        float dx = zv.x - qv.x, dy = zv.y - qv.y, dzv = zv.z - qv.z, dw = zv.w - qv.w;
        lacc += dx * dx + dy * dy + dzv * dzv + dw * dw;
        float* ep = esT + (size_t)k * 256 + d;
        atomicAdd(ep + 0, zv.x);
        atomicAdd(ep + 1, zv.y);
        atomicAdd(ep + 2, zv.z);
        atomicAdd(ep + 3, zv.w);
        if (lane == 0) atomicAdd(counts + k, 1);
    }
#pragma unroll
    for (int o = 32; o > 0; o >>= 1) lacc += __shfl_down(lacc, o, 64);
    __shared__ float sbuf[4];
    if (lane == 0) sbuf[wv] = lacc;
    __syncthreads();
    if (t == 0) atomicAdd(lossSum, sbuf[0] + sbuf[1] + sbuf[2] + sbuf[3]);
}

// ---------------- cluster_size_new + n + loss finalize ----------------
__global__ __launch_bounds__(1024) void csn_kernel(const float* __restrict__ cluster_size,
                                                   const int* __restrict__ counts,
                                                   float* __restrict__ out3,
                                                   float* __restrict__ out1,
                                                   const float* __restrict__ lossSum,
                                                   float* __restrict__ nOut) {
    int k = threadIdx.x;
    float cn = cluster_size[k] * DECAYC + (1.f - DECAYC) * (float)counts[k];
    out3[k] = cn;
    float v = cn;
#pragma unroll
    for (int o = 32; o > 0; o >>= 1) v += __shfl_down(v, o, 64);
    __shared__ float sbuf[16];
    int lane = k & 63, wv = k >> 6;
    if (lane == 0) sbuf[wv] = v;
    __syncthreads();
    if (k == 0) {
        float n = 0.f;
#pragma unroll
        for (int i = 0; i < 16; ++i) n += sbuf[i];
        nOut[0] = n;
        out1[0] = 0.25f * lossSum[0] / 16777216.0f;
    }
}

// ---------------- embedding_mean_new + embedding_new (psum variant) ----------------
__global__ __launch_bounds__(256) void final8_kernel(const float* __restrict__ embedding_mean,
                                                     const float* __restrict__ psum,
                                                     const float* __restrict__ csn,
                                                     const float* __restrict__ nPtr,
                                                     float* __restrict__ out2,
                                                     float* __restrict__ out4) {
    int tid = blockIdx.x * 256 + threadIdx.x;
    int d = tid >> 10;
    int k = tid & 1023;
    const float* p = psum + (size_t)k * 8 * 256 + d;
    float es = 0.f;
#pragma unroll
    for (int s = 0; s < 8; ++s) es += p[s * 256];
    float emn = embedding_mean[tid] * DECAYC + (1.f - DECAYC) * es;
    out4[tid] = emn;
    float n = nPtr[0];
    float c = csn[k];
    float cs = (c + EPSQ) / (n + 1024.f * EPSQ) * n;
    out2[tid] = emn / cs;
}

// ---------------- embedding_mean_new + embedding_new (esT fallback) ----------------
__global__ __launch_bounds__(256) void final_kernel(const float* __restrict__ embedding_mean,
                                                    const float* __restrict__ esT,
                                                    const float* __restrict__ csn,
                                                    const float* __restrict__ nPtr,
                                                    float* __restrict__ out2,
                                                    float* __restrict__ out4) {
    int tid = blockIdx.x * 256 + threadIdx.x;
    int d = tid >> 10;
    int k = tid & 1023;
    float es = esT[(size_t)k * 256 + d];
    float emn = embedding_mean[tid] * DECAYC + (1.f - DECAYC) * es;
    out4[tid] = emn;
    float n = nPtr[0];
    float c = csn[k];
    float cs = (c + EPSQ) / (n + 1024.f * EPSQ) * n;
    out2[tid] = emn / cs;
}

extern "C" void kernel_launch(void* const* d_in, const int* in_sizes, int n_in,
                              void* d_out, int out_size, void* d_ws, size_t ws_size,
                              hipStream_t stream) {
    const float* z = (const float*)d_in[0];
    const float* E = (const float*)d_in[1];
    const float* cluster_size = (const float*)d_in[2];
    const float* embedding_mean = (const float*)d_in[3];

    float* out0 = (float*)d_out;        // z_q_st
    float* out1 = out0 + 16777216;      // vq_loss
    float* out2 = out1 + 1;             // embedding_new
    float* out3 = out2 + 262144;        // cluster_size_new
    float* out4 = out3 + 1024;          // embedding_mean_new

    // ws layout (float units)
    float* ws = (float*)d_ws;
    float* colnorm = ws;                         // 1024
    int* idx = (int*)(ws + 1024);                // 65536
    int* counts = (int*)(ws + 66560);            // 1024   (zeroed)
    float* esT = ws + 67584;                     // 262144 (fallback only, zeroed)
    float* lossSum = ws + 329728;                // 1      (zeroed)
    float* nOut = ws + 329729;                   // 1
    float* ET = ws + 329732;                     // 262144 fp32 [k][d]
    ushort_t* zh = (ushort_t*)(ws + 591876);     // 16777216 bf16
    ushort_t* zl = (ushort_t*)(ws + 8980484);    // 16777216 bf16
    ushort_t* Eph = (ushort_t*)(ws + 17369092);  // 262144 bf16 packed
    ushort_t* Epl = (ushort_t*)(ws + 17500164);  // 262144 bf16 packed
    const size_t needed = 17631236ull * 4ull;    // ~70.5 MB

    // aliases into zh/zl region — only used AFTER dist_mfma_kernel
    float* psum = ws + 591876;                   // 2097152 floats (8 slices x 1024 x 256)
    int* sorted = (int*)(ws + 2689028);          // 65536
    int* offsets = (int*)(ws + 2754564);         // 1025
    int* cursor = (int*)(ws + 2755592);          // 1024

    hipMemsetAsync(counts, 0, (size_t)(1024 + 262144 + 1) * sizeof(float), stream);

    colnorm_kernel<<<4, 256, 0, stream>>>(E, colnorm);
    transpose_kernel<<<1024, 256, 0, stream>>>(E, ET);

    if (ws_size >= needed) {
        prep_z_kernel<<<16384, 256, 0, stream>>>(z, zh, zl);
        prep_E_kernel<<<128, 256, 0, stream>>>(E, Eph, Epl);
        dist_mfma_kernel<<<512, 256, 0, stream>>>(zh, zl, Eph, Epl, colnorm, idx);

        gather_loss_kernel<<<4096, 256, 0, stream>>>(z, ET, idx, out0, lossSum);
        hist_kernel<<<256, 256, 0, stream>>>(idx, counts);
        prefix_kernel<<<1, 1024, 0, stream>>>(counts, offsets, cursor);
        scatter_sort_kernel<<<256, 256, 0, stream>>>(idx, offsets, cursor, sorted);
        segsum_kernel<<<8192, 256, 0, stream>>>(z, sorted, offsets, psum);
        csn_kernel<<<1, 1024, 0, stream>>>(cluster_size, counts, out3, out1, lossSum, nOut);
        final8_kernel<<<1024, 256, 0, stream>>>(embedding_mean, psum, out3, nOut, out2, out4);
    } else {
        dist_argmin_kernel<<<1024, 256, 0, stream>>>(z, E, colnorm, idx);
        gather_scatter_kernel<<<4096, 256, 0, stream>>>(z, ET, idx, out0, esT, counts, lossSum);
        csn_kernel<<<1, 1024, 0, stream>>>(cluster_size, counts, out3, out1, lossSum, nOut);
        final_kernel<<<1024, 256, 0, stream>>>(embedding_mean, esT, out3, nOut, out2, out4);
    }
}

// Round 5
// 401.186 us; speedup vs baseline: 2.4707x; 1.2949x over previous
//
#include <hip/hip_runtime.h>

// z: [16,4096,256] fp32 -> N=65536 rows, d=256
// embedding: [256,1024], cluster_size: [1024], embedding_mean: [256,1024]

#define DECAYC 0.99f
#define EPSQ 1e-5f

typedef unsigned short ushort_t;
typedef __attribute__((ext_vector_type(8))) short bf16x8;
typedef __attribute__((ext_vector_type(4))) float f32x4;
typedef unsigned long long u64;

__device__ __forceinline__ ushort_t f2bf(float x) {
    unsigned u = __float_as_uint(x);
    unsigned r = (u + 0x7FFFu + ((u >> 16) & 1u)) >> 16;   // RNE
    return (ushort_t)r;
}
__device__ __forceinline__ float bf2f(ushort_t h) {
    return __uint_as_float(((unsigned)h) << 16);
}
__device__ __forceinline__ u64 umin64(u64 a, u64 b) { return a < b ? a : b; }
__device__ __forceinline__ void async_cp16(const void* g, void* l) {
    __builtin_amdgcn_global_load_lds(
        (const __attribute__((address_space(1))) void*)g,
        (__attribute__((address_space(3))) void*)l, 16, 0, 0);
}

// ---------------- E-side prep (fused): ET + colnorm + Eph/Epl ----------------
// block n = code (1024 blocks), thread d = dim (256)
__global__ __launch_bounds__(256) void prep_E_kernel(const float* __restrict__ E,
                                                     float* __restrict__ ET,
                                                     float* __restrict__ colnorm,
                                                     ushort_t* __restrict__ Eph,
                                                     ushort_t* __restrict__ Epl) {
    int n = blockIdx.x;
    int d = threadIdx.x;
    float v = E[d * 1024 + n];
    ET[n * 256 + d] = v;
    ushort_t h = f2bf(v);
    ushort_t l = f2bf(v - bf2f(h));
    size_t pi = ((size_t)(d >> 3) * 1024 + n) * 8 + (d & 7);
    Eph[pi] = h;
    Epl[pi] = l;
    __shared__ float red[256];
    red[d] = v * v;
    __syncthreads();
    for (int o = 128; o > 0; o >>= 1) {
        if (d < o) red[d] += red[d + o];
        __syncthreads();
    }
    if (d == 0) colnorm[n] = red[0];
}

// ---------------- MFMA distance + argmin (z resident in LDS) ----------------
// Block: 64 rows x 1024 codes. 256 thr = 4 waves, 2x2 of (32 rows x 64 codes).
// Split-bf16: acc += Ah*Bh + Ah*Bl + Al*Bh.
__global__ __launch_bounds__(256, 2) void dist_mfma_kernel(const float* __restrict__ z,
                                                           const ushort_t* __restrict__ Eph,
                                                           const ushort_t* __restrict__ Epl,
                                                           const float* __restrict__ colnorm,
                                                           int* __restrict__ idxOut) {
    // A: fragment-packed slots (kq*64 + r)*8, kq=0..31, r=0..63  -> 32 KB each
    __shared__ __align__(16) ushort_t Ah[16384];
    __shared__ __align__(16) ushort_t Al[16384];
    // B: slots (q*128 + c)*8, q=0..3, c=0..127 -> 8 KB each
    __shared__ __align__(16) ushort_t Bh[4096];
    __shared__ __align__(16) ushort_t Bl[4096];
    // total 80 KB -> 2 blocks/CU

    const int t = threadIdx.x;
    const int lane = t & 63;
    const int w = t >> 6;          // wave 0..3
    const int wrow = w >> 1;       // 0..1
    const int wcol = w & 1;        // 0..1
    const int n16 = lane & 15;
    const int q = lane >> 4;       // 0..3
    const int rowBase = blockIdx.x * 64;

    // ---- one-time: convert this block's 64 z rows to bf16 hi/lo in LDS ----
#pragma unroll
    for (int i = 0; i < 8; ++i) {
        int s = i * 256 + t;       // slot 0..2047: kq = s>>6, r = s&63
        int kq = s >> 6;
        int r = s & 63;
        const float* gp = z + (size_t)(rowBase + r) * 256 + kq * 8;
        float4 v0 = *(const float4*)gp;
        float4 v1 = *(const float4*)(gp + 4);
        float vv[8] = {v0.x, v0.y, v0.z, v0.w, v1.x, v1.y, v1.z, v1.w};
        ushort_t hh[8], ll[8];
#pragma unroll
        for (int j = 0; j < 8; ++j) {
            hh[j] = f2bf(vv[j]);
            ll[j] = f2bf(vv[j] - bf2f(hh[j]));
        }
        ushort4 h0 = {hh[0], hh[1], hh[2], hh[3]}, h1 = {hh[4], hh[5], hh[6], hh[7]};
        ushort4 l0 = {ll[0], ll[1], ll[2], ll[3]}, l1 = {ll[4], ll[5], ll[6], ll[7]};
        *(ushort4*)&Ah[s * 8] = h0;
        *(ushort4*)&Ah[s * 8 + 4] = h1;
        *(ushort4*)&Al[s * 8] = l0;
        *(ushort4*)&Al[s * 8 + 4] = l1;
    }

    u64 best[2][4];
#pragma unroll
    for (int rt = 0; rt < 2; ++rt)
#pragma unroll
        for (int reg = 0; reg < 4; ++reg) best[rt][reg] = ~0ull;

    for (int cb = 0; cb < 8; ++cb) {
        const int cBase = cb * 128;
        f32x4 acc[2][4];
#pragma unroll
        for (int rt = 0; rt < 2; ++rt)
#pragma unroll
            for (int ct = 0; ct < 4; ++ct) acc[rt][ct] = (f32x4){0.f, 0.f, 0.f, 0.f};

        for (int ks = 0; ks < 8; ++ks) {
            __syncthreads();   // prior readers of Bh/Bl done (also covers conversion on first iter)
            // stage B tile (16 KB from L2): wave w covers q=w, two 64-code chunks
            const ushort_t* gh = Eph + ((size_t)(ks * 4 + w) * 1024 + cBase) * 8;
            const ushort_t* gl = Epl + ((size_t)(ks * 4 + w) * 1024 + cBase) * 8;
            async_cp16(gh + (size_t)lane * 8,        &Bh[(w * 128 + 0) * 8]);
            async_cp16(gh + (size_t)(64 + lane) * 8, &Bh[(w * 128 + 64) * 8]);
            async_cp16(gl + (size_t)lane * 8,        &Bl[(w * 128 + 0) * 8]);
            async_cp16(gl + (size_t)(64 + lane) * 8, &Bl[(w * 128 + 64) * 8]);
            __syncthreads();   // drains vmcnt -> staging visible

            bf16x8 afh[2], afl[2], bfh[4], bfl[4];
#pragma unroll
            for (int rt = 0; rt < 2; ++rt) {
                int ao = ((ks * 4 + q) * 64 + wrow * 32 + rt * 16 + n16) * 8;
                afh[rt] = *(const bf16x8*)&Ah[ao];
                afl[rt] = *(const bf16x8*)&Al[ao];
            }
#pragma unroll
            for (int ct = 0; ct < 4; ++ct) {
                int bo = (q * 128 + wcol * 64 + ct * 16 + n16) * 8;
                bfh[ct] = *(const bf16x8*)&Bh[bo];
                bfl[ct] = *(const bf16x8*)&Bl[bo];
            }
#pragma unroll
            for (int rt = 0; rt < 2; ++rt)
#pragma unroll
                for (int ct = 0; ct < 4; ++ct) {
                    acc[rt][ct] = __builtin_amdgcn_mfma_f32_16x16x32_bf16(afh[rt], bfh[ct], acc[rt][ct], 0, 0, 0);
                    acc[rt][ct] = __builtin_amdgcn_mfma_f32_16x16x32_bf16(afh[rt], bfl[ct], acc[rt][ct], 0, 0, 0);
                    acc[rt][ct] = __builtin_amdgcn_mfma_f32_16x16x32_bf16(afl[rt], bfh[ct], acc[rt][ct], 0, 0, 0);
                }
        }

        // per-chunk argmin: dist = colnorm[c] - 2*dot (||z||^2 const per row)
        float cn[4];
#pragma unroll
        for (int ct = 0; ct < 4; ++ct) cn[ct] = colnorm[cBase + wcol * 64 + ct * 16 + n16];
#pragma unroll
        for (int rt = 0; rt < 2; ++rt)
#pragma unroll
            for (int reg = 0; reg < 4; ++reg) {
                u64 b = best[rt][reg];
#pragma unroll
                for (int ct = 0; ct < 4; ++ct) {
                    float dist = cn[ct] - 2.f * acc[rt][ct][reg];
                    unsigned fb = __float_as_uint(dist);
                    unsigned sk = (fb & 0x80000000u) ? ~fb : (fb | 0x80000000u);
                    unsigned code = (unsigned)(cBase + wcol * 64 + ct * 16 + n16);
                    b = umin64(b, ((u64)sk << 32) | code);
                }
                b = umin64(b, __shfl_xor(b, 1, 64));
                b = umin64(b, __shfl_xor(b, 2, 64));
                b = umin64(b, __shfl_xor(b, 4, 64));
                b = umin64(b, __shfl_xor(b, 8, 64));
                best[rt][reg] = b;
            }
    }

    // merge the two wcol halves via LDS (reuse Bh region)
    __syncthreads();
    u64* bl = (u64*)Bh;   // 128 u64 = 1 KB
    if (n16 == 0) {
#pragma unroll
        for (int rt = 0; rt < 2; ++rt)
#pragma unroll
            for (int reg = 0; reg < 4; ++reg)
                bl[wcol * 64 + wrow * 32 + rt * 16 + q * 4 + reg] = best[rt][reg];
    }
    __syncthreads();
    if (t < 64)
        idxOut[rowBase + t] = (int)(unsigned)(umin64(bl[t], bl[64 + t]) & 0xFFFFFFFFull);
}

// ---------------- gather z_q + loss + int histogram ----------------
__global__ __launch_bounds__(256) void gather_loss_kernel(const float* __restrict__ z,
                                                          const float* __restrict__ ET,
                                                          const int* __restrict__ idx,
                                                          float* __restrict__ out0,
                                                          float* __restrict__ lossSum,
                                                          int* __restrict__ counts) {
    const int t = threadIdx.x;
    const int lane = t & 63;
    const int wv = t >> 6;
    float lacc = 0.f;
    for (int g = blockIdx.x; g < 16384; g += gridDim.x) {
        int row = g * 4 + wv;
        int k = idx[row];
        int d = lane * 4;
        float4 zv = *(const float4*)(z + (size_t)row * 256 + d);
        float4 qv = *(const float4*)(ET + (size_t)k * 256 + d);
        *(float4*)(out0 + (size_t)row * 256 + d) = qv;
        float dx = zv.x - qv.x, dy = zv.y - qv.y, dzv = zv.z - qv.z, dw = zv.w - qv.w;
        lacc += dx * dx + dy * dy + dzv * dzv + dw * dw;
        if (lane == 0) atomicAdd(counts + k, 1);
    }
#pragma unroll
    for (int o = 32; o > 0; o >>= 1) lacc += __shfl_down(lacc, o, 64);
    __shared__ float sbuf[4];
    if (lane == 0) sbuf[wv] = lacc;
    __syncthreads();
    if (t == 0) atomicAdd(lossSum, sbuf[0] + sbuf[1] + sbuf[2] + sbuf[3]);
}

// ---------------- prefix scan + cluster_size_new + n + loss finalize ----------------
__global__ __launch_bounds__(1024) void prefix_csn_kernel(const int* __restrict__ counts,
                                                          const float* __restrict__ cluster_size,
                                                          const float* __restrict__ lossSum,
                                                          int* __restrict__ offsets,
                                                          int* __restrict__ cursor,
                                                          float* __restrict__ out3,
                                                          float* __restrict__ out1,
                                                          float* __restrict__ nOut) {
    __shared__ int sbuf[1024];
    int t = threadIdx.x;
    int c = counts[t];
    sbuf[t] = c;
    __syncthreads();
    for (int off = 1; off < 1024; off <<= 1) {
        int v = (t >= off) ? sbuf[t - off] : 0;
        __syncthreads();
        sbuf[t] += v;
        __syncthreads();
    }
    offsets[t] = sbuf[t] - c;
    if (t == 1023) offsets[1024] = sbuf[1023];
    cursor[t] = 0;

    float cn = cluster_size[t] * DECAYC + (1.f - DECAYC) * (float)c;
    out3[t] = cn;
    float v = cn;
#pragma unroll
    for (int o = 32; o > 0; o >>= 1) v += __shfl_down(v, o, 64);
    __shared__ float fbuf[16];
    int lane = t & 63, wv = t >> 6;
    if (lane == 0) fbuf[wv] = v;
    __syncthreads();
    if (t == 0) {
        float n = 0.f;
#pragma unroll
        for (int i = 0; i < 16; ++i) n += fbuf[i];
        nOut[0] = n;
        out1[0] = 0.25f * lossSum[0] / 16777216.0f;
    }
}

// ---------------- scatter row ids into code-sorted order ----------------
__global__ __launch_bounds__(256) void scatter_sort_kernel(const int* __restrict__ idx,
                                                           const int* __restrict__ offsets,
                                                           int* __restrict__ cursor,
                                                           int* __restrict__ sorted) {
    int i = blockIdx.x * 256 + threadIdx.x;
    int k = idx[i];
    int pos = atomicAdd(cursor + k, 1);
    sorted[offsets[k] + pos] = i;
}

// ---------------- segmented sum: psum[(k*8+s)*256+d] (no atomics) ----------------
__global__ __launch_bounds__(256) void segsum_kernel(const float* __restrict__ z,
                                                     const int* __restrict__ sorted,
                                                     const int* __restrict__ offsets,
                                                     float* __restrict__ psum) {
    const int k = blockIdx.x >> 3;
    const int s = blockIdx.x & 7;
    const int t = threadIdx.x;
    const int lane = t & 63;
    const int w = t >> 6;
    const int start = offsets[k], end = offsets[k + 1];
    float4 acc = {0.f, 0.f, 0.f, 0.f};
    for (int j = start + s * 4 + w; j < end; j += 32) {
        int row = sorted[j];
        float4 v = *(const float4*)(z + (size_t)row * 256 + lane * 4);
        acc.x += v.x; acc.y += v.y; acc.z += v.z; acc.w += v.w;
    }
    __shared__ float red[4][256];
    *(float4*)&red[w][lane * 4] = acc;
    __syncthreads();
    float v = red[0][t] + red[1][t] + red[2][t] + red[3][t];
    psum[((size_t)k * 8 + s) * 256 + t] = v;
}

// ---------------- embedding_mean_new + embedding_new ----------------
__global__ __launch_bounds__(256) void final8_kernel(const float* __restrict__ embedding_mean,
                                                     const float* __restrict__ psum,
                                                     const float* __restrict__ csn,
                                                     const float* __restrict__ nPtr,
                                                     float* __restrict__ out2,
                                                     float* __restrict__ out4) {
    int tid = blockIdx.x * 256 + threadIdx.x;
    int d = tid >> 10;
    int k = tid & 1023;
    const float* p = psum + (size_t)k * 8 * 256 + d;
    float es = 0.f;
#pragma unroll
    for (int s = 0; s < 8; ++s) es += p[s * 256];
    float emn = embedding_mean[tid] * DECAYC + (1.f - DECAYC) * es;
    out4[tid] = emn;
    float n = nPtr[0];
    float c = csn[k];
    float cs = (c + EPSQ) / (n + 1024.f * EPSQ) * n;
    out2[tid] = emn / cs;
}

extern "C" void kernel_launch(void* const* d_in, const int* in_sizes, int n_in,
                              void* d_out, int out_size, void* d_ws, size_t ws_size,
                              hipStream_t stream) {
    const float* z = (const float*)d_in[0];
    const float* E = (const float*)d_in[1];
    const float* cluster_size = (const float*)d_in[2];
    const float* embedding_mean = (const float*)d_in[3];

    float* out0 = (float*)d_out;        // z_q_st
    float* out1 = out0 + 16777216;      // vq_loss
    float* out2 = out1 + 1;             // embedding_new
    float* out3 = out2 + 262144;        // cluster_size_new
    float* out4 = out3 + 1024;          // embedding_mean_new

    // ws layout (float units)
    float* ws = (float*)d_ws;
    float* colnorm = ws;                         // 1024
    int* idx = (int*)(ws + 1024);                // 65536
    int* counts = (int*)(ws + 66560);            // 1024  (zeroed)
    float* lossSum = ws + 67584;                 // 1     (zeroed, contiguous w/ counts)
    float* nOut = ws + 67585;                    // 1
    float* ET = ws + 67588;                      // 262144 fp32 [k][d]
    ushort_t* Eph = (ushort_t*)(ws + 329732);    // 262144 ushort (131072 fl)
    ushort_t* Epl = (ushort_t*)(ws + 460804);    // 262144 ushort
    float* psum = ws + 591876;                   // 2097152
    int* sorted = (int*)(ws + 2689028);          // 65536
    int* offsets = (int*)(ws + 2754564);         // 1025
    int* cursor = (int*)(ws + 2755592);          // 1024
    // needed ~11 MB << ws_size (>=70 MB confirmed in prior rounds)

    hipMemsetAsync(counts, 0, (size_t)1025 * sizeof(float), stream);   // counts + lossSum

    prep_E_kernel<<<1024, 256, 0, stream>>>(E, ET, colnorm, Eph, Epl);
    dist_mfma_kernel<<<1024, 256, 0, stream>>>(z, Eph, Epl, colnorm, idx);
    gather_loss_kernel<<<4096, 256, 0, stream>>>(z, ET, idx, out0, lossSum, counts);
    prefix_csn_kernel<<<1, 1024, 0, stream>>>(counts, cluster_size, lossSum,
                                              offsets, cursor, out3, out1, nOut);
    scatter_sort_kernel<<<256, 256, 0, stream>>>(idx, offsets, cursor, sorted);
    segsum_kernel<<<8192, 256, 0, stream>>>(z, sorted, offsets, psum);
    final8_kernel<<<1024, 256, 0, stream>>>(embedding_mean, psum, out3, nOut, out2, out4);
}

// Round 6
// 386.439 us; speedup vs baseline: 2.5650x; 1.0382x over previous
//
#include <hip/hip_runtime.h>

// z: [16,4096,256] fp32 -> N=65536 rows, d=256
// embedding: [256,1024], cluster_size: [1024], embedding_mean: [256,1024]

#define DECAYC 0.99f
#define EPSQ 1e-5f

typedef unsigned short ushort_t;
typedef __attribute__((ext_vector_type(8))) short bf16x8;
typedef __attribute__((ext_vector_type(4))) float f32x4;
typedef unsigned long long u64;

__device__ __forceinline__ ushort_t f2bf(float x) {
    unsigned u = __float_as_uint(x);
    unsigned r = (u + 0x7FFFu + ((u >> 16) & 1u)) >> 16;   // RNE
    return (ushort_t)r;
}
__device__ __forceinline__ float bf2f(ushort_t h) {
    return __uint_as_float(((unsigned)h) << 16);
}
__device__ __forceinline__ u64 umin64(u64 a, u64 b) { return a < b ? a : b; }

// ---------------- E-side prep (fused): ET + colnorm + Eph/Epl ----------------
__global__ __launch_bounds__(256) void prep_E_kernel(const float* __restrict__ E,
                                                     float* __restrict__ ET,
                                                     float* __restrict__ colnorm,
                                                     ushort_t* __restrict__ Eph,
                                                     ushort_t* __restrict__ Epl) {
    int n = blockIdx.x;
    int d = threadIdx.x;
    float v = E[d * 1024 + n];
    ET[n * 256 + d] = v;
    ushort_t h = f2bf(v);
    ushort_t l = f2bf(v - bf2f(h));
    size_t pi = ((size_t)(d >> 3) * 1024 + n) * 8 + (d & 7);
    Eph[pi] = h;
    Epl[pi] = l;
    __shared__ float red[256];
    red[d] = v * v;
    __syncthreads();
    for (int o = 128; o > 0; o >>= 1) {
        if (d < o) red[d] += red[d + o];
        __syncthreads();
    }
    if (d == 0) colnorm[n] = red[0];
}

// ---------------- MFMA distance + argmin ----------------
// Block: 64 rows x 1024 codes. 256 thr = 4 waves, 2x2 of (32 rows x 64 codes).
// A (z hi/lo bf16) resident in LDS (one barrier total). B fragments loaded
// directly global->VGPR per lane (contiguous 16 B in packed Eph/Epl) — the
// cb/ks loops contain NO barriers, so the compiler pipelines loads freely
// and waves never block on a vmcnt(0) drain.
__global__ __launch_bounds__(256, 2) void dist_mfma_kernel(const float* __restrict__ z,
                                                           const ushort_t* __restrict__ Eph,
                                                           const ushort_t* __restrict__ Epl,
                                                           const float* __restrict__ colnorm,
                                                           int* __restrict__ idxOut) {
    // A: fragment-packed slots (kq*64 + r)*8, kq=0..31, r=0..63 -> 32 KB each
    __shared__ __align__(16) ushort_t Ah[16384];
    __shared__ __align__(16) ushort_t Al[16384];

    const int t = threadIdx.x;
    const int lane = t & 63;
    const int w = t >> 6;          // wave 0..3
    const int wrow = w >> 1;       // 0..1
    const int wcol = w & 1;        // 0..1
    const int n16 = lane & 15;
    const int q = lane >> 4;       // 0..3
    const int rowBase = blockIdx.x * 64;

    // ---- one-time: convert this block's 64 z rows to bf16 hi/lo in LDS ----
#pragma unroll
    for (int i = 0; i < 8; ++i) {
        int s = i * 256 + t;       // slot: kq = s>>6, r = s&63
        int kq = s >> 6;
        int r = s & 63;
        const float* gp = z + (size_t)(rowBase + r) * 256 + kq * 8;
        float4 v0 = *(const float4*)gp;
        float4 v1 = *(const float4*)(gp + 4);
        float vv[8] = {v0.x, v0.y, v0.z, v0.w, v1.x, v1.y, v1.z, v1.w};
        ushort_t hh[8], ll[8];
#pragma unroll
        for (int j = 0; j < 8; ++j) {
            hh[j] = f2bf(vv[j]);
            ll[j] = f2bf(vv[j] - bf2f(hh[j]));
        }
        ushort4 h0 = {hh[0], hh[1], hh[2], hh[3]}, h1 = {hh[4], hh[5], hh[6], hh[7]};
        ushort4 l0 = {ll[0], ll[1], ll[2], ll[3]}, l1 = {ll[4], ll[5], ll[6], ll[7]};
        *(ushort4*)&Ah[s * 8] = h0;
        *(ushort4*)&Ah[s * 8 + 4] = h1;
        *(ushort4*)&Al[s * 8] = l0;
        *(ushort4*)&Al[s * 8 + 4] = l1;
    }
    __syncthreads();   // the ONLY barrier before the epilogue merge

    u64 best[2][4];
#pragma unroll
    for (int rt = 0; rt < 2; ++rt)
#pragma unroll
        for (int reg = 0; reg < 4; ++reg) best[rt][reg] = ~0ull;

    for (int cb = 0; cb < 8; ++cb) {
        const int cBase = cb * 128;
        f32x4 acc[2][4];
#pragma unroll
        for (int rt = 0; rt < 2; ++rt)
#pragma unroll
            for (int ct = 0; ct < 4; ++ct) acc[rt][ct] = (f32x4){0.f, 0.f, 0.f, 0.f};

#pragma unroll
        for (int ks = 0; ks < 8; ++ks) {
            // B fragments: direct global->VGPR, 16 B contiguous per lane.
            // Lane (n16,q) needs B[n = cBase + wcol*64 + ct*16 + n16][kq = ks*4+q].
            bf16x8 bfh[4], bfl[4];
            const size_t bbase = ((size_t)(ks * 4 + q) * 1024 + cBase + wcol * 64 + n16) * 8;
#pragma unroll
            for (int ct = 0; ct < 4; ++ct) {
                bfh[ct] = *(const bf16x8*)(Eph + bbase + ct * 128);
                bfl[ct] = *(const bf16x8*)(Epl + bbase + ct * 128);
            }
            bf16x8 afh[2], afl[2];
#pragma unroll
            for (int rt = 0; rt < 2; ++rt) {
                int ao = ((ks * 4 + q) * 64 + wrow * 32 + rt * 16 + n16) * 8;
                afh[rt] = *(const bf16x8*)&Ah[ao];
                afl[rt] = *(const bf16x8*)&Al[ao];
            }
#pragma unroll
            for (int rt = 0; rt < 2; ++rt)
#pragma unroll
                for (int ct = 0; ct < 4; ++ct) {
                    acc[rt][ct] = __builtin_amdgcn_mfma_f32_16x16x32_bf16(afh[rt], bfh[ct], acc[rt][ct], 0, 0, 0);
                    acc[rt][ct] = __builtin_amdgcn_mfma_f32_16x16x32_bf16(afh[rt], bfl[ct], acc[rt][ct], 0, 0, 0);
                    acc[rt][ct] = __builtin_amdgcn_mfma_f32_16x16x32_bf16(afl[rt], bfh[ct], acc[rt][ct], 0, 0, 0);
                }
        }

        // per-chunk argmin: dist = colnorm[c] - 2*dot  (||z||^2 const per row)
        float cn[4];
#pragma unroll
        for (int ct = 0; ct < 4; ++ct) cn[ct] = colnorm[cBase + wcol * 64 + ct * 16 + n16];
#pragma unroll
        for (int rt = 0; rt < 2; ++rt)
#pragma unroll
            for (int reg = 0; reg < 4; ++reg) {
                u64 b = best[rt][reg];
#pragma unroll
                for (int ct = 0; ct < 4; ++ct) {
                    float dist = cn[ct] - 2.f * acc[rt][ct][reg];
                    unsigned fb = __float_as_uint(dist);
                    unsigned sk = (fb & 0x80000000u) ? ~fb : (fb | 0x80000000u);
                    unsigned code = (unsigned)(cBase + wcol * 64 + ct * 16 + n16);
                    b = umin64(b, ((u64)sk << 32) | code);
                }
                b = umin64(b, __shfl_xor(b, 1, 64));
                b = umin64(b, __shfl_xor(b, 2, 64));
                b = umin64(b, __shfl_xor(b, 4, 64));
                b = umin64(b, __shfl_xor(b, 8, 64));
                best[rt][reg] = b;
            }
    }

    // merge the two wcol halves via LDS (reuse Ah region)
    __syncthreads();   // all waves done with Ah/Al reads
    u64* bl = (u64*)Ah;   // 128 u64 = 1 KB
    if (n16 == 0) {
#pragma unroll
        for (int rt = 0; rt < 2; ++rt)
#pragma unroll
            for (int reg = 0; reg < 4; ++reg)
                bl[wcol * 64 + wrow * 32 + rt * 16 + q * 4 + reg] = best[rt][reg];
    }
    __syncthreads();
    if (t < 64)
        idxOut[rowBase + t] = (int)(unsigned)(umin64(bl[t], bl[64 + t]) & 0xFFFFFFFFull);
}

// ---------------- gather z_q + loss + int histogram ----------------
__global__ __launch_bounds__(256) void gather_loss_kernel(const float* __restrict__ z,
                                                          const float* __restrict__ ET,
                                                          const int* __restrict__ idx,
                                                          float* __restrict__ out0,
                                                          float* __restrict__ lossSum,
                                                          int* __restrict__ counts) {
    const int t = threadIdx.x;
    const int lane = t & 63;
    const int wv = t >> 6;
    float lacc = 0.f;
    for (int g = blockIdx.x; g < 16384; g += gridDim.x) {
        int row = g * 4 + wv;
        int k = idx[row];
        int d = lane * 4;
        float4 zv = *(const float4*)(z + (size_t)row * 256 + d);
        float4 qv = *(const float4*)(ET + (size_t)k * 256 + d);
        *(float4*)(out0 + (size_t)row * 256 + d) = qv;
        float dx = zv.x - qv.x, dy = zv.y - qv.y, dzv = zv.z - qv.z, dw = zv.w - qv.w;
        lacc += dx * dx + dy * dy + dzv * dzv + dw * dw;
        if (lane == 0) atomicAdd(counts + k, 1);
    }
#pragma unroll
    for (int o = 32; o > 0; o >>= 1) lacc += __shfl_down(lacc, o, 64);
    __shared__ float sbuf[4];
    if (lane == 0) sbuf[wv] = lacc;
    __syncthreads();
    if (t == 0) atomicAdd(lossSum, sbuf[0] + sbuf[1] + sbuf[2] + sbuf[3]);
}

// ---------------- prefix scan + cluster_size_new + n + loss finalize ----------------
__global__ __launch_bounds__(1024) void prefix_csn_kernel(const int* __restrict__ counts,
                                                          const float* __restrict__ cluster_size,
                                                          const float* __restrict__ lossSum,
                                                          int* __restrict__ offsets,
                                                          int* __restrict__ cursor,
                                                          float* __restrict__ out3,
                                                          float* __restrict__ out1,
                                                          float* __restrict__ nOut) {
    __shared__ int sbuf[1024];
    int t = threadIdx.x;
    int c = counts[t];
    sbuf[t] = c;
    __syncthreads();
    for (int off = 1; off < 1024; off <<= 1) {
        int v = (t >= off) ? sbuf[t - off] : 0;
        __syncthreads();
        sbuf[t] += v;
        __syncthreads();
    }
    offsets[t] = sbuf[t] - c;
    if (t == 1023) offsets[1024] = sbuf[1023];
    cursor[t] = 0;

    float cn = cluster_size[t] * DECAYC + (1.f - DECAYC) * (float)c;
    out3[t] = cn;
    float v = cn;
#pragma unroll
    for (int o = 32; o > 0; o >>= 1) v += __shfl_down(v, o, 64);
    __shared__ float fbuf[16];
    int lane = t & 63, wv = t >> 6;
    if (lane == 0) fbuf[wv] = v;
    __syncthreads();
    if (t == 0) {
        float n = 0.f;
#pragma unroll
        for (int i = 0; i < 16; ++i) n += fbuf[i];
        nOut[0] = n;
        out1[0] = 0.25f * lossSum[0] / 16777216.0f;
    }
}

// ---------------- scatter row ids into code-sorted order ----------------
__global__ __launch_bounds__(256) void scatter_sort_kernel(const int* __restrict__ idx,
                                                           const int* __restrict__ offsets,
                                                           int* __restrict__ cursor,
                                                           int* __restrict__ sorted) {
    int i = blockIdx.x * 256 + threadIdx.x;
    int k = idx[i];
    int pos = atomicAdd(cursor + k, 1);
    sorted[offsets[k] + pos] = i;
}

// ---------------- segmented sum: psum[(k*8+s)*256+d] (no atomics) ----------------
__global__ __launch_bounds__(256) void segsum_kernel(const float* __restrict__ z,
                                                     const int* __restrict__ sorted,
                                                     const int* __restrict__ offsets,
                                                     float* __restrict__ psum) {
    const int k = blockIdx.x >> 3;
    const int s = blockIdx.x & 7;
    const int t = threadIdx.x;
    const int lane = t & 63;
    const int w = t >> 6;
    const int start = offsets[k], end = offsets[k + 1];
    float4 acc = {0.f, 0.f, 0.f, 0.f};
    for (int j = start + s * 4 + w; j < end; j += 32) {
        int row = sorted[j];
        float4 v = *(const float4*)(z + (size_t)row * 256 + lane * 4);
        acc.x += v.x; acc.y += v.y; acc.z += v.z; acc.w += v.w;
    }
    __shared__ float red[4][256];
    *(float4*)&red[w][lane * 4] = acc;
    __syncthreads();
    float v = red[0][t] + red[1][t] + red[2][t] + red[3][t];
    psum[((size_t)k * 8 + s) * 256 + t] = v;
}

// ---------------- embedding_mean_new + embedding_new ----------------
__global__ __launch_bounds__(256) void final8_kernel(const float* __restrict__ embedding_mean,
                                                     const float* __restrict__ psum,
                                                     const float* __restrict__ csn,
                                                     const float* __restrict__ nPtr,
                                                     float* __restrict__ out2,
                                                     float* __restrict__ out4) {
    int tid = blockIdx.x * 256 + threadIdx.x;
    int d = tid >> 10;
    int k = tid & 1023;
    const float* p = psum + (size_t)k * 8 * 256 + d;
    float es = 0.f;
#pragma unroll
    for (int s = 0; s < 8; ++s) es += p[s * 256];
    float emn = embedding_mean[tid] * DECAYC + (1.f - DECAYC) * es;
    out4[tid] = emn;
    float n = nPtr[0];
    float c = csn[k];
    float cs = (c + EPSQ) / (n + 1024.f * EPSQ) * n;
    out2[tid] = emn / cs;
}

extern "C" void kernel_launch(void* const* d_in, const int* in_sizes, int n_in,
                              void* d_out, int out_size, void* d_ws, size_t ws_size,
                              hipStream_t stream) {
    const float* z = (const float*)d_in[0];
    const float* E = (const float*)d_in[1];
    const float* cluster_size = (const float*)d_in[2];
    const float* embedding_mean = (const float*)d_in[3];

    float* out0 = (float*)d_out;        // z_q_st
    float* out1 = out0 + 16777216;      // vq_loss
    float* out2 = out1 + 1;             // embedding_new
    float* out3 = out2 + 262144;        // cluster_size_new
    float* out4 = out3 + 1024;          // embedding_mean_new

    // ws layout (float units)
    float* ws = (float*)d_ws;
    float* colnorm = ws;                         // 1024
    int* idx = (int*)(ws + 1024);                // 65536
    int* counts = (int*)(ws + 66560);            // 1024  (zeroed)
    float* lossSum = ws + 67584;                 // 1     (zeroed, contiguous w/ counts)
    float* nOut = ws + 67585;                    // 1
    float* ET = ws + 67588;                      // 262144 fp32 [k][d]
    ushort_t* Eph = (ushort_t*)(ws + 329732);    // 262144 ushort
    ushort_t* Epl = (ushort_t*)(ws + 460804);    // 262144 ushort
    float* psum = ws + 591876;                   // 2097152
    int* sorted = (int*)(ws + 2689028);          // 65536
    int* offsets = (int*)(ws + 2754564);         // 1025
    int* cursor = (int*)(ws + 2755592);          // 1024

    hipMemsetAsync(counts, 0, (size_t)1025 * sizeof(float), stream);   // counts + lossSum

    prep_E_kernel<<<1024, 256, 0, stream>>>(E, ET, colnorm, Eph, Epl);
    dist_mfma_kernel<<<1024, 256, 0, stream>>>(z, Eph, Epl, colnorm, idx);
    gather_loss_kernel<<<4096, 256, 0, stream>>>(z, ET, idx, out0, lossSum, counts);
    prefix_csn_kernel<<<1, 1024, 0, stream>>>(counts, cluster_size, lossSum,
                                              offsets, cursor, out3, out1, nOut);
    scatter_sort_kernel<<<256, 256, 0, stream>>>(idx, offsets, cursor, sorted);
    segsum_kernel<<<8192, 256, 0, stream>>>(z, sorted, offsets, psum);
    final8_kernel<<<1024, 256, 0, stream>>>(embedding_mean, psum, out3, nOut, out2, out4);
}

// Round 7
// 328.523 us; speedup vs baseline: 3.0172x; 1.1763x over previous
//
#include <hip/hip_runtime.h>

// z: [16,4096,256] fp32 -> N=65536 rows, d=256
// embedding: [256,1024], cluster_size: [1024], embedding_mean: [256,1024]

#define DECAYC 0.99f
#define EPSQ 1e-5f

typedef unsigned short ushort_t;
typedef __attribute__((ext_vector_type(8))) short bf16x8;
typedef __attribute__((ext_vector_type(4))) float f32x4;
typedef unsigned long long u64;

__device__ __forceinline__ ushort_t f2bf(float x) {
    unsigned u = __float_as_uint(x);
    unsigned r = (u + 0x7FFFu + ((u >> 16) & 1u)) >> 16;   // RNE
    return (ushort_t)r;
}
__device__ __forceinline__ float bf2f(ushort_t h) {
    return __uint_as_float(((unsigned)h) << 16);
}
__device__ __forceinline__ u64 umin64(u64 a, u64 b) { return a < b ? a : b; }

// ---------------- E-side prep (fused): ET + colnorm + Eph/Epl + zero stats ----------------
__global__ __launch_bounds__(256) void prep_E_kernel(const float* __restrict__ E,
                                                     float* __restrict__ ET,
                                                     float* __restrict__ colnorm,
                                                     ushort_t* __restrict__ Eph,
                                                     ushort_t* __restrict__ Epl,
                                                     int* __restrict__ counts,
                                                     float* __restrict__ lossSum) {
    int n = blockIdx.x;
    int d = threadIdx.x;
    if (d == 0) counts[n] = 0;               // zero stats (replaces memset dispatch)
    if (n == 0 && d == 1) lossSum[0] = 0.f;
    float v = E[d * 1024 + n];
    ET[n * 256 + d] = v;
    ushort_t h = f2bf(v);
    ushort_t l = f2bf(v - bf2f(h));
    size_t pi = ((size_t)(d >> 3) * 1024 + n) * 8 + (d & 7);
    Eph[pi] = h;
    Epl[pi] = l;
    __shared__ float red[256];
    red[d] = v * v;
    __syncthreads();
    for (int o = 128; o > 0; o >>= 1) {
        if (d < o) red[d] += red[d + o];
        __syncthreads();
    }
    if (d == 0) colnorm[n] = red[0];
}

// ---------------- MFMA distance + argmin + fused gather/loss/hist ----------------
// Block: 64 rows x 1024 codes. 256 thr = 4 waves, 2x2 of (32 rows x 64 codes).
// A (z hi/lo bf16) resident in LDS; B fragments direct global->VGPR (no barriers
// in the cb/ks loops). Cross-lane argmin reduction hoisted AFTER the cb loop
// (numerically identical: u64 keys total-order; min associative; ties -> lowest code).
__global__ __launch_bounds__(256, 2) void dist_mfma_kernel(const float* __restrict__ z,
                                                           const ushort_t* __restrict__ Eph,
                                                           const ushort_t* __restrict__ Epl,
                                                           const float* __restrict__ colnorm,
                                                           const float* __restrict__ ET,
                                                           float* __restrict__ out0,
                                                           float* __restrict__ lossSum,
                                                           int* __restrict__ counts,
                                                           int* __restrict__ idxOut) {
    __shared__ __align__(16) ushort_t Ah[16384];   // slots (kq*64+r)*8, 32 KB
    __shared__ __align__(16) ushort_t Al[16384];
    __shared__ float sred[4];

    const int t = threadIdx.x;
    const int lane = t & 63;
    const int w = t >> 6;          // wave 0..3
    const int wrow = w >> 1;       // 0..1
    const int wcol = w & 1;        // 0..1
    const int n16 = lane & 15;
    const int q = lane >> 4;       // 0..3
    const int rowBase = blockIdx.x * 64;

    // ---- one-time: convert this block's 64 z rows to bf16 hi/lo in LDS ----
#pragma unroll
    for (int i = 0; i < 8; ++i) {
        int s = i * 256 + t;       // slot: kq = s>>6, r = s&63
        int kq = s >> 6;
        int r = s & 63;
        const float* gp = z + (size_t)(rowBase + r) * 256 + kq * 8;
        float4 v0 = *(const float4*)gp;
        float4 v1 = *(const float4*)(gp + 4);
        float vv[8] = {v0.x, v0.y, v0.z, v0.w, v1.x, v1.y, v1.z, v1.w};
        ushort_t hh[8], ll[8];
#pragma unroll
        for (int j = 0; j < 8; ++j) {
            hh[j] = f2bf(vv[j]);
            ll[j] = f2bf(vv[j] - bf2f(hh[j]));
        }
        ushort4 h0 = {hh[0], hh[1], hh[2], hh[3]}, h1 = {hh[4], hh[5], hh[6], hh[7]};
        ushort4 l0 = {ll[0], ll[1], ll[2], ll[3]}, l1 = {ll[4], ll[5], ll[6], ll[7]};
        *(ushort4*)&Ah[s * 8] = h0;
        *(ushort4*)&Ah[s * 8 + 4] = h1;
        *(ushort4*)&Al[s * 8] = l0;
        *(ushort4*)&Al[s * 8 + 4] = l1;
    }
    __syncthreads();

    u64 best[2][4];
#pragma unroll
    for (int rt = 0; rt < 2; ++rt)
#pragma unroll
        for (int reg = 0; reg < 4; ++reg) best[rt][reg] = ~0ull;

    for (int cb = 0; cb < 8; ++cb) {
        const int cBase = cb * 128;
        f32x4 acc[2][4];
#pragma unroll
        for (int rt = 0; rt < 2; ++rt)
#pragma unroll
            for (int ct = 0; ct < 4; ++ct) acc[rt][ct] = (f32x4){0.f, 0.f, 0.f, 0.f};

#pragma unroll
        for (int ks = 0; ks < 8; ++ks) {
            bf16x8 bfh[4], bfl[4];
            const size_t bbase = ((size_t)(ks * 4 + q) * 1024 + cBase + wcol * 64 + n16) * 8;
#pragma unroll
            for (int ct = 0; ct < 4; ++ct) {
                bfh[ct] = *(const bf16x8*)(Eph + bbase + ct * 128);
                bfl[ct] = *(const bf16x8*)(Epl + bbase + ct * 128);
            }
            bf16x8 afh[2], afl[2];
#pragma unroll
            for (int rt = 0; rt < 2; ++rt) {
                int ao = ((ks * 4 + q) * 64 + wrow * 32 + rt * 16 + n16) * 8;
                afh[rt] = *(const bf16x8*)&Ah[ao];
                afl[rt] = *(const bf16x8*)&Al[ao];
            }
#pragma unroll
            for (int rt = 0; rt < 2; ++rt)
#pragma unroll
                for (int ct = 0; ct < 4; ++ct) {
                    acc[rt][ct] = __builtin_amdgcn_mfma_f32_16x16x32_bf16(afh[rt], bfh[ct], acc[rt][ct], 0, 0, 0);
                    acc[rt][ct] = __builtin_amdgcn_mfma_f32_16x16x32_bf16(afh[rt], bfl[ct], acc[rt][ct], 0, 0, 0);
                    acc[rt][ct] = __builtin_amdgcn_mfma_f32_16x16x32_bf16(afl[rt], bfh[ct], acc[rt][ct], 0, 0, 0);
                }
        }

        // lane-local argmin update only (no cross-lane work inside the cb loop)
        float cn[4];
#pragma unroll
        for (int ct = 0; ct < 4; ++ct) cn[ct] = colnorm[cBase + wcol * 64 + ct * 16 + n16];
#pragma unroll
        for (int rt = 0; rt < 2; ++rt)
#pragma unroll
            for (int reg = 0; reg < 4; ++reg) {
                u64 b = best[rt][reg];
#pragma unroll
                for (int ct = 0; ct < 4; ++ct) {
                    float dist = cn[ct] - 2.f * acc[rt][ct][reg];
                    unsigned fb = __float_as_uint(dist);
                    unsigned sk = (fb & 0x80000000u) ? ~fb : (fb | 0x80000000u);
                    unsigned code = (unsigned)(cBase + wcol * 64 + ct * 16 + n16);
                    b = umin64(b, ((u64)sk << 32) | code);
                }
                best[rt][reg] = b;
            }
    }

    // one-time cross-lane reduction (within each 16-lane col group)
#pragma unroll
    for (int rt = 0; rt < 2; ++rt)
#pragma unroll
        for (int reg = 0; reg < 4; ++reg) {
            u64 b = best[rt][reg];
            b = umin64(b, __shfl_xor(b, 1, 64));
            b = umin64(b, __shfl_xor(b, 2, 64));
            b = umin64(b, __shfl_xor(b, 4, 64));
            b = umin64(b, __shfl_xor(b, 8, 64));
            best[rt][reg] = b;
        }

    __syncthreads();               // done reading Ah/Al
    u64* bl = (u64*)Ah;            // 128 u64
    int* kArr = (int*)Al;          // 64 ints
    if (n16 == 0) {
#pragma unroll
        for (int rt = 0; rt < 2; ++rt)
#pragma unroll
            for (int reg = 0; reg < 4; ++reg)
                bl[wcol * 64 + wrow * 32 + rt * 16 + q * 4 + reg] = best[rt][reg];
    }
    __syncthreads();
    if (t < 64) {
        int k = (int)(unsigned)(umin64(bl[t], bl[64 + t]) & 0xFFFFFFFFull);
        idxOut[rowBase + t] = k;
        kArr[t] = k;
        atomicAdd(counts + k, 1);
    }
    __syncthreads();

    // ---- fused gather z_q + loss: wave w handles rows w*16..w*16+15 ----
    float lacc = 0.f;
#pragma unroll
    for (int i = 0; i < 16; ++i) {
        int r = w * 16 + i;
        int k = kArr[r];
        const float* ep = ET + (size_t)k * 256 + lane * 4;
        const float* zp = z + (size_t)(rowBase + r) * 256 + lane * 4;
        float4 qv = *(const float4*)ep;
        float4 zv = *(const float4*)zp;
        *(float4*)(out0 + (size_t)(rowBase + r) * 256 + lane * 4) = qv;
        float dx = zv.x - qv.x, dy = zv.y - qv.y, dz = zv.z - qv.z, dw = zv.w - qv.w;
        lacc += dx * dx + dy * dy + dz * dz + dw * dw;
    }
#pragma unroll
    for (int o = 32; o > 0; o >>= 1) lacc += __shfl_down(lacc, o, 64);
    if (lane == 0) sred[w] = lacc;
    __syncthreads();
    if (t == 0) atomicAdd(lossSum, sred[0] + sred[1] + sred[2] + sred[3]);
}

// ---------------- prefix scan + cluster_size_new + n + loss finalize ----------------
__global__ __launch_bounds__(1024) void prefix_csn_kernel(const int* __restrict__ counts,
                                                          const float* __restrict__ cluster_size,
                                                          const float* __restrict__ lossSum,
                                                          int* __restrict__ offsets,
                                                          int* __restrict__ cursor,
                                                          float* __restrict__ out3,
                                                          float* __restrict__ out1,
                                                          float* __restrict__ nOut) {
    __shared__ int sbuf[1024];
    int t = threadIdx.x;
    int c = counts[t];
    sbuf[t] = c;
    __syncthreads();
    for (int off = 1; off < 1024; off <<= 1) {
        int v = (t >= off) ? sbuf[t - off] : 0;
        __syncthreads();
        sbuf[t] += v;
        __syncthreads();
    }
    offsets[t] = sbuf[t] - c;
    if (t == 1023) offsets[1024] = sbuf[1023];
    cursor[t] = 0;

    float cn = cluster_size[t] * DECAYC + (1.f - DECAYC) * (float)c;
    out3[t] = cn;
    float v = cn;
#pragma unroll
    for (int o = 32; o > 0; o >>= 1) v += __shfl_down(v, o, 64);
    __shared__ float fbuf[16];
    int lane = t & 63, wv = t >> 6;
    if (lane == 0) fbuf[wv] = v;
    __syncthreads();
    if (t == 0) {
        float n = 0.f;
#pragma unroll
        for (int i = 0; i < 16; ++i) n += fbuf[i];
        nOut[0] = n;
        out1[0] = 0.25f * lossSum[0] / 16777216.0f;
    }
}

// ---------------- scatter row ids into code-sorted order ----------------
__global__ __launch_bounds__(256) void scatter_sort_kernel(const int* __restrict__ idx,
                                                           const int* __restrict__ offsets,
                                                           int* __restrict__ cursor,
                                                           int* __restrict__ sorted) {
    int i = blockIdx.x * 256 + threadIdx.x;
    int k = idx[i];
    int pos = atomicAdd(cursor + k, 1);
    sorted[offsets[k] + pos] = i;
}

// ---------------- segmented sum: psum[(k*8+s)*256+d] (no atomics) ----------------
__global__ __launch_bounds__(256) void segsum_kernel(const float* __restrict__ z,
                                                     const int* __restrict__ sorted,
                                                     const int* __restrict__ offsets,
                                                     float* __restrict__ psum) {
    const int k = blockIdx.x >> 3;
    const int s = blockIdx.x & 7;
    const int t = threadIdx.x;
    const int lane = t & 63;
    const int w = t >> 6;
    const int start = offsets[k], end = offsets[k + 1];
    float4 acc = {0.f, 0.f, 0.f, 0.f};
    for (int j = start + s * 4 + w; j < end; j += 32) {
        int row = sorted[j];
        float4 v = *(const float4*)(z + (size_t)row * 256 + lane * 4);
        acc.x += v.x; acc.y += v.y; acc.z += v.z; acc.w += v.w;
    }
    __shared__ float red[4][256];
    *(float4*)&red[w][lane * 4] = acc;
    __syncthreads();
    float v = red[0][t] + red[1][t] + red[2][t] + red[3][t];
    psum[((size_t)k * 8 + s) * 256 + t] = v;
}

// ---------------- embedding_mean_new + embedding_new ----------------
__global__ __launch_bounds__(256) void final8_kernel(const float* __restrict__ embedding_mean,
                                                     const float* __restrict__ psum,
                                                     const float* __restrict__ csn,
                                                     const float* __restrict__ nPtr,
                                                     float* __restrict__ out2,
                                                     float* __restrict__ out4) {
    int tid = blockIdx.x * 256 + threadIdx.x;
    int d = tid >> 10;
    int k = tid & 1023;
    const float* p = psum + (size_t)k * 8 * 256 + d;
    float es = 0.f;
#pragma unroll
    for (int s = 0; s < 8; ++s) es += p[s * 256];
    float emn = embedding_mean[tid] * DECAYC + (1.f - DECAYC) * es;
    out4[tid] = emn;
    float n = nPtr[0];
    float c = csn[k];
    float cs = (c + EPSQ) / (n + 1024.f * EPSQ) * n;
    out2[tid] = emn / cs;
}

extern "C" void kernel_launch(void* const* d_in, const int* in_sizes, int n_in,
                              void* d_out, int out_size, void* d_ws, size_t ws_size,
                              hipStream_t stream) {
    const float* z = (const float*)d_in[0];
    const float* E = (const float*)d_in[1];
    const float* cluster_size = (const float*)d_in[2];
    const float* embedding_mean = (const float*)d_in[3];

    float* out0 = (float*)d_out;        // z_q_st
    float* out1 = out0 + 16777216;      // vq_loss
    float* out2 = out1 + 1;             // embedding_new
    float* out3 = out2 + 262144;        // cluster_size_new
    float* out4 = out3 + 1024;          // embedding_mean_new

    // ws layout (float units)
    float* ws = (float*)d_ws;
    float* colnorm = ws;                         // 1024
    int* idx = (int*)(ws + 1024);                // 65536
    int* counts = (int*)(ws + 66560);            // 1024  (zeroed in prep_E)
    float* lossSum = ws + 67584;                 // 1     (zeroed in prep_E)
    float* nOut = ws + 67585;                    // 1
    float* ET = ws + 67588;                      // 262144 fp32 [k][d]
    ushort_t* Eph = (ushort_t*)(ws + 329732);    // 262144 ushort
    ushort_t* Epl = (ushort_t*)(ws + 460804);    // 262144 ushort
    float* psum = ws + 591876;                   // 2097152
    int* sorted = (int*)(ws + 2689028);          // 65536
    int* offsets = (int*)(ws + 2754564);         // 1025
    int* cursor = (int*)(ws + 2755592);          // 1024

    prep_E_kernel<<<1024, 256, 0, stream>>>(E, ET, colnorm, Eph, Epl, counts, lossSum);
    dist_mfma_kernel<<<1024, 256, 0, stream>>>(z, Eph, Epl, colnorm, ET,
                                               out0, lossSum, counts, idx);
    prefix_csn_kernel<<<1, 1024, 0, stream>>>(counts, cluster_size, lossSum,
                                              offsets, cursor, out3, out1, nOut);
    scatter_sort_kernel<<<256, 256, 0, stream>>>(idx, offsets, cursor, sorted);
    segsum_kernel<<<8192, 256, 0, stream>>>(z, sorted, offsets, psum);
    final8_kernel<<<1024, 256, 0, stream>>>(embedding_mean, psum, out3, nOut, out2, out4);
}